// Round 12
// baseline (450.535 us; speedup 1.0000x reference)
//
#include <hip/hip_runtime.h>
#include <hip/hip_bf16.h>
#include <math.h>

typedef __hip_bfloat16 bf16;
typedef short short8 __attribute__((ext_vector_type(8)));   // bf16x8 MFMA frag (4 VGPRs)
typedef float f32x4 __attribute__((ext_vector_type(4)));    // MFMA accumulator
typedef unsigned short us4 __attribute__((ext_vector_type(4)));

static __device__ __forceinline__ float b2f(bf16 x) { return __bfloat162float(x); }
static __device__ __forceinline__ bf16  f2b(float x) { return __float2bfloat16(x); }
static __device__ __forceinline__ short f2bs(float x) { bf16 t = f2b(x); return *reinterpret_cast<short*>(&t); }
static __device__ __forceinline__ float ex2(float x) { float r; asm("v_exp_f32 %0, %1" : "=v"(r) : "v"(x)); return r; }

// Polymorphic input load: isb=true -> bf16 storage, else f32 storage.
static __device__ __forceinline__ float ldin(const void* p, size_t i, bool isb) {
    return isb ? b2f(((const bf16*)p)[i]) : ((const float*)p)[i];
}

// ---------------------------------------------------------------- dtype detect (+ zero strip fill)
__global__ void detect_kernel(const unsigned int* __restrict__ x, float* __restrict__ flagp,
                              unsigned int* __restrict__ zstrip) {
    __shared__ int sh[64];
    for (int i = threadIdx.x; i < 256; i += 64) zstrip[i] = 0u;
    int insane = 0;
    for (int i = threadIdx.x; i < 1024; i += 64) {
        unsigned int lo = (x[i] & 0xFFFFu) << 16;
        float v = __uint_as_float(lo);
        if (!(fabsf(v) <= 1e6f)) insane++;
    }
    sh[threadIdx.x] = insane;
    __syncthreads();
    if (threadIdx.x == 0) {
        int t = 0;
        for (int i = 0; i < 64; ++i) t += sh[i];
        *flagp = (t < 16) ? 1.f : 0.f;            // 1 => inputs are bf16
    }
}

// ---------------------------------------------------------------- diagnostic fill
__global__ void diag_fill(unsigned int* __restrict__ out, int nwords, float val) {
    int i = blockIdx.x * blockDim.x + threadIdx.x;
    if (i < nwords) {
        unsigned short h = (unsigned short)(__float_as_uint(val) >> 16);
        out[i] = ((unsigned int)h << 16) | h;
    }
}

// ---------------------------------------------------------------- weight pack: [co][ci][tap] -> [tap][co][ci] bf16
__global__ void wpack_kernel(const void* __restrict__ wt, const float* __restrict__ flg,
                             bf16* __restrict__ dst, int Cout, int Cin) {
    bool isb = (*flg != 0.f);
    int n = Cout * Cin * 9;
    int idx = blockIdx.x * blockDim.x + threadIdx.x;
    if (idx >= n) return;
    int ci = idx % Cin;
    int co = (idx / Cin) % Cout;
    int tap = idx / (Cin * Cout);
    dst[idx] = f2b(ldin(wt, ((size_t)co * Cin + ci) * 9 + tap, isb));
}

// ---------------------------------------------------------------- flat convert to bf16 (caun kw pack)
__global__ void b2bpack(const void* __restrict__ src, const float* __restrict__ flg,
                        bf16* __restrict__ dst, int n) {
    bool isb = (*flg != 0.f);
    int i = blockIdx.x * blockDim.x + threadIdx.x;
    if (i < n) dst[i] = f2b(ldin(src, i, isb));
}

// ---------------------------------------------------------------- NCHW ext -> channels-last bf16 (LDS tile transpose)
// G13 vectorization: bf16 path loads are pure copies -> ushort4 8B/lane;
// writes gather 4 c's -> one 8B store. Same tile mapping.
__global__ void nchw2cl(const void* __restrict__ in, const float* __restrict__ flg,
                        bf16* __restrict__ out, int C, int HW) {
    __shared__ bf16 t[32][72];
    bool isb = (*flg != 0.f);
    int npx = HW >> 6, nc = C >> 5;
    int blk = blockIdx.x;
    int px0 = (blk % npx) << 6;
    int c0  = ((blk / npx) % nc) << 5;
    int b   = blk / (npx * nc);
    if (isb) {
        const bf16* pin = (const bf16*)in;
        for (int i = threadIdx.x; i < 512; i += 256) {
            int px4 = (i & 15) << 2, c = i >> 4;
            *(us4*)&t[c][px4] =
                *(const us4*)(pin + ((size_t)(b * C + c0 + c)) * HW + px0 + px4);
        }
    } else {
        const float* pf = (const float*)in;
        for (int i = threadIdx.x; i < 512; i += 256) {
            int px4 = (i & 15) << 2, c = i >> 4;
            float4 v = *(const float4*)(pf + ((size_t)(b * C + c0 + c)) * HW + px0 + px4);
            t[c][px4 + 0] = f2b(v.x);
            t[c][px4 + 1] = f2b(v.y);
            t[c][px4 + 2] = f2b(v.z);
            t[c][px4 + 3] = f2b(v.w);
        }
    }
    __syncthreads();
    for (int i = threadIdx.x; i < 512; i += 256) {
        int px = i >> 3, c4 = (i & 7) << 2;
        us4 v;
        v[0] = *(const unsigned short*)&t[c4 + 0][px];
        v[1] = *(const unsigned short*)&t[c4 + 1][px];
        v[2] = *(const unsigned short*)&t[c4 + 2][px];
        v[3] = *(const unsigned short*)&t[c4 + 3][px];
        *(us4*)&out[((size_t)b * HW + px0 + px) * C + c0 + c4] = v;
    }
}

// ---------------------------------------------------------------- 2x2 mean pool: NCHW ext -> channels-last bf16 ws
// Paired [2w,2w+1] loads merged into one 4B/8B vector load per row.
__global__ void pool2_cl(const void* __restrict__ in, const float* __restrict__ flg,
                         bf16* __restrict__ out, int B, int C, int H2, int W2) {
    bool isb = (*flg != 0.f);
    int idx = blockIdx.x * blockDim.x + threadIdx.x;
    int total = B * H2 * W2 * C;
    if (idx >= total) return;
    int c = idx % C;
    int pix = idx / C;
    int w = pix % W2;
    int h = (pix / W2) % H2;
    int b = pix / (W2 * H2);
    int H = H2 * 2, W = W2 * 2;
    size_t base = ((size_t)(b * C + c)) * H * W + (size_t)(2 * h) * W + 2 * w;
    float s;
    if (isb) {
        const bf16* pin = (const bf16*)in;
        unsigned int a = *(const unsigned int*)(pin + base);
        unsigned int d = *(const unsigned int*)(pin + base + W);
        float v00 = __uint_as_float(a << 16);
        float v01 = __uint_as_float(a & 0xFFFF0000u);
        float v10 = __uint_as_float(d << 16);
        float v11 = __uint_as_float(d & 0xFFFF0000u);
        s = v00 + v01 + v10 + v11;
    } else {
        const float* pf = (const float*)in;
        float2 r0 = *(const float2*)(pf + base);
        float2 r1 = *(const float2*)(pf + base + W);
        s = r0.x + r0.y + r1.x + r1.y;
    }
    out[idx] = f2b(0.25f * s);
}

// ---------------------------------------------------------------- MFMA conv3x3, LDS-staged, double-buffered
// Proven round-4/7 w_s structure. Round-24: RT=1 EVERYWHERE — convs are
// occupancy-capped (MfmaUtil ~4.5%, Occ ~37%): RT=1 LDS 36.3KB -> 4 blocks/CU
// (vs 3 at 46.7KB) AND 2x grid. Cost: halo redundancy 1.25->1.5x (HBM at 2%,
// irrelevant) + 2x weight-LDS/barrier totals vs +33% resident waves.
template<int RT>
__global__ __launch_bounds__(256) void conv3x3_lds(
        const bf16* __restrict__ in1, int C1,
        const bf16* __restrict__ in2, int C2,
        const bf16* __restrict__ wp,
        const void* __restrict__ bias,
        const void* __restrict__ alpha,
        const float* __restrict__ flg,
        const char* __restrict__ zs,
        bf16* __restrict__ out,
        int H, int W, int Cout, int act) {
    constexpr int NRB = 4 * RT + 2;            // staged rows
    constexpr int NIU = NRB * 18 * 4;          // input 16B units
    constexpr int KI = (NIU + 255) / 256;
    constexpr int KW = 3;                      // 576 weight units / 256
    __shared__ bf16 in_s[2][NRB][18][36];      // [buf][row][px][ci pad 32->36]
    __shared__ bf16 w_s[2][9][16][36];         // [buf][tap][cout][ci pad]

    const bool isb = (*flg != 0.f);
    const int Cin = C1 + C2;
    const int tid = threadIdx.x;
    const int lane = tid & 63, wave = tid >> 6;
    const int quad = lane >> 4, l16 = lane & 15;
    const int cot = Cout >> 4;
    const int b = blockIdx.z / cot;
    const int co_base = (blockIdx.z % cot) << 4;
    const int r0b = blockIdx.y * (4 * RT);
    const int c0 = blockIdx.x << 4;
    const int cog = co_base + l16;

    // ---- chunk-invariant per-thread staging addresses
    const char* pin1[KI];
    const char* pin2[KI];
    #pragma unroll
    for (int k = 0; k < KI; ++k) {
        int u = min(tid + k * 256, NIU - 1);
        int sub = u & 3, px = (u >> 2) % 18, row = (u >> 2) / 18;
        int ih = r0b + row - 1, iw = c0 + px - 1;
        bool ok = (ih >= 0) && (ih < H) && (iw >= 0) && (iw < W);
        int ihc = min(max(ih, 0), H - 1), iwc = min(max(iw, 0), W - 1);
        size_t pix = (size_t)(b * H + ihc) * W + iwc;
        pin1[k] = (ok && C1 > 0) ? (const char*)(in1 + pix * C1 + sub * 8) : (zs + sub * 16);
        pin2[k] = ok ? (const char*)(in2 + pix * C2 + sub * 8) : (zs + sub * 16);
    }
    size_t offw[KW];
    #pragma unroll
    for (int k = 0; k < KW; ++k) {
        int u = min(tid + k * 256, 575);
        int sub = u & 3, cw = (u >> 2) & 15, tap = u >> 6;
        offw[k] = ((size_t)(tap * Cout + co_base + cw) * Cin + sub * 8) * 2;
    }
    const char* pw = (const char*)wp;

    short8 rin[KI], rwt[KW];
    auto issue = [&](int ci0) {
        const bool f1 = ci0 < C1;
        const int cl2 = (f1 ? ci0 : ci0 - C1) * 2;
        #pragma unroll
        for (int k = 0; k < KI; ++k)
            rin[k] = *(const short8*)((f1 ? pin1[k] : pin2[k]) + cl2);
        #pragma unroll
        for (int k = 0; k < KW; ++k)
            rwt[k] = *(const short8*)(pw + offw[k] + (size_t)ci0 * 2);
    };
    auto commit = [&](int bufi) {
        #pragma unroll
        for (int k = 0; k < KI; ++k) {
            int u = tid + k * 256;
            if (u < NIU) {
                int sub = u & 3, px = (u >> 2) % 18, row = (u >> 2) / 18;
                *(short8*)&in_s[bufi][row][px][sub * 8] = rin[k];
            }
        }
        #pragma unroll
        for (int k = 0; k < KW; ++k) {
            int u = tid + k * 256;
            if (u < 576) {
                int sub = u & 3, cw = (u >> 2) & 15, tap = u >> 6;
                *(short8*)&w_s[bufi][tap][cw][sub * 8] = rwt[k];
            }
        }
    };

    float bv = ldin(bias, cog, isb);
    f32x4 acc[RT];
    #pragma unroll
    for (int t = 0; t < RT; ++t) acc[t] = {bv, bv, bv, bv};

    const int nchunk = Cin >> 5;
    issue(0);
    commit(0);
    __syncthreads();
    int buf = 0;
    for (int ic = 0; ic < nchunk; ++ic) {
        const bool nx = (ic + 1 < nchunk);
        if (nx) issue((ic + 1) << 5);           // loads in flight over compute
        #pragma unroll
        for (int kw = 0; kw < 3; ++kw) {
            short8 F[RT + 2];
            #pragma unroll
            for (int j = 0; j < RT + 2; ++j)
                F[j] = *(const short8*)&in_s[buf][wave * RT + j][l16 + kw][quad * 8];
            #pragma unroll
            for (int kh = 0; kh < 3; ++kh) {
                short8 Wk = *(const short8*)&w_s[buf][kh * 3 + kw][l16][quad * 8];
                #pragma unroll
                for (int t = 0; t < RT; ++t)
                    acc[t] = __builtin_amdgcn_mfma_f32_16x16x32_bf16(F[t + kh], Wk, acc[t], 0, 0, 0);
            }
        }
        if (nx) commit(buf ^ 1);                // vmcnt drain lands here, post-compute
        __syncthreads();
        buf ^= 1;
    }

    float a = (act == 2) ? ldin(alpha, cog, isb) : 0.f;
    const int r0 = r0b + wave * RT;
    #pragma unroll
    for (int t = 0; t < RT; ++t) {
        #pragma unroll
        for (int reg = 0; reg < 4; ++reg) {
            float v = acc[t][reg];
            if (act == 1) v = fmaxf(v, 0.f);
            else if (act == 2) v = (v >= 0.f) ? v : a * v;
            out[(((size_t)(b * H) + r0 + t) * W + c0 + (quad << 2) + reg) * Cout + cog] = f2b(v);
        }
    }
}

// ---------------------------------------------------------------- MFMA conv3x3, ext-NCHW fallback
template<int RT>
__global__ __launch_bounds__(256) void conv3x3_ext(
        const void* __restrict__ in1, int C1,
        const bf16* __restrict__ in2, int C2,
        const bf16* __restrict__ wp,
        const void* __restrict__ bias,
        const void* __restrict__ alpha,
        const float* __restrict__ flg,
        bf16* __restrict__ out,
        int H, int W, int Cout, int act) {
    const bool isb = (*flg != 0.f);
    const int Cin = C1 + C2;
    const int lane = threadIdx.x & 63;
    const int wave = threadIdx.x >> 6;
    const int quad = lane >> 4, l16 = lane & 15;
    const int cot = Cout >> 4;
    const int b = blockIdx.z / cot;
    const int co_base = (blockIdx.z % cot) << 4;
    const int r0 = (blockIdx.y * 4 + wave) * RT;
    const int c0 = blockIdx.x << 4;
    const int cog = co_base + l16;

    float bv = ldin(bias, cog, isb);
    f32x4 acc[RT];
    #pragma unroll
    for (int t = 0; t < RT; ++t) acc[t] = {bv, bv, bv, bv};

    for (int ci0 = 0; ci0 < Cin; ci0 += 32) {
        const bool from1 = (ci0 < C1);
        #pragma unroll
        for (int kw = 0; kw < 3; ++kw) {
            const int iw = c0 + l16 + kw - 1;
            const bool okc = (iw >= 0) && (iw < W);
            short8 F[RT + 2];
            #pragma unroll
            for (int j = 0; j < RT + 2; ++j) {
                const int ih = r0 + j - 1;
                const bool ok = okc && (ih >= 0) && (ih < H);
                F[j] = short8{0, 0, 0, 0, 0, 0, 0, 0};
                if (from1) {
                    if (ok) {
                        size_t base = ((size_t)(b * C1 + ci0 + quad * 8)) * H * W
                                    + (size_t)ih * W + iw;
                        #pragma unroll
                        for (int jj = 0; jj < 8; ++jj)
                            F[j][jj] = f2bs(ldin(in1, base + (size_t)jj * H * W, isb));
                    }
                } else {
                    if (ok)
                        F[j] = *(const short8*)&in2[(((size_t)(b * H) + ih) * W + iw) * C2
                                                     + (ci0 - C1) + quad * 8];
                }
            }
            #pragma unroll
            for (int kh = 0; kh < 3; ++kh) {
                short8 bfrag = *(const short8*)&wp[((size_t)(kh * 3 + kw) * Cout + cog) * Cin
                                                   + ci0 + quad * 8];
                #pragma unroll
                for (int t = 0; t < RT; ++t)
                    acc[t] = __builtin_amdgcn_mfma_f32_16x16x32_bf16(F[t + kh], bfrag, acc[t], 0, 0, 0);
            }
        }
    }

    float a = (act == 2) ? ldin(alpha, cog, isb) : 0.f;
    #pragma unroll
    for (int t = 0; t < RT; ++t) {
        #pragma unroll
        for (int reg = 0; reg < 4; ++reg) {
            float v = acc[t][reg];
            if (act == 1) v = fmaxf(v, 0.f);
            else if (act == 2) v = (v >= 0.f) ? v : a * v;
            out[(((size_t)(b * H) + r0 + t) * W + c0 + (quad << 2) + reg) * Cout + cog] = f2b(v);
        }
    }
}

// ---------------------------------------------------------------- CAUN v5 (CC=8): unchanged (anchor)
template<int CC>
__global__ __launch_bounds__(256) void caun_v5(
        const bf16* __restrict__ f,
        const void* __restrict__ xlow, int xext,
        const bf16* __restrict__ kwp,
        const void* __restrict__ kb,
        const float* __restrict__ flg,
        bf16* __restrict__ out,
        int C, int K, int H, int W) {
    __shared__ float kb_s[CC * 40];             // [c][36 pad 40]
    __shared__ bf16  neigh_s[100 * (CC + 2)];   // [cell][c pad]
    __shared__ bf16  out_s[256 * (CC + 2)];     // [slot][c pad]

    const bool isb = (*flg != 0.f);
    const int tw = W >> 3;
    const int h0 = (blockIdx.x / tw) << 3;
    const int w0 = (blockIdx.x % tw) << 3;
    const int b  = blockIdx.y;
    const int c0 = blockIdx.z * CC;
    const int tid = threadIdx.x, wave = tid >> 6, lane = tid & 63;
    const int quad = lane >> 4, l16 = lane & 15;

    // ---- stage clamped neighbor halo (c-contiguous loads)
    for (int i = tid; i < 100 * CC; i += 256) {
        int c = i % CC, cell = i / CC;
        int r = cell / 10, q = cell % 10;
        int ih = min(max(h0 + r - 1, 0), H - 1);
        int iw = min(max(w0 + q - 1, 0), W - 1);
        float v = xext
            ? ldin(xlow, ((size_t)(b * C + c0 + c)) * H * W + (size_t)ih * W + iw, isb)
            : b2f(((const bf16*)xlow)[(((size_t)(b * H) + ih) * W + iw) * C + c0 + c]);
        neigh_s[cell * (CC + 2) + c] = f2b(v);
    }
    // ---- stage bias chunk, [c][j] layout (j-contiguous global reads)
    for (int i = tid; i < 36 * CC; i += 256) {
        int j = i % 36, c = i / 36;
        kb_s[c * 40 + j] = ldin(kb, (size_t)(c0 + c) * 36 + j, isb);
    }

    // ---- hoist B-frags (f) for this wave's 16 px (2 input rows x 8 cols)
    const int hl = (wave << 1) + (l16 >> 3);
    const int wl = l16 & 7;
    const size_t fpx = ((size_t)b * H * W + (size_t)(h0 + hl) * W + (w0 + wl)) * K;
    const int nkc = ((K + 31) & ~31) >> 5;          // 1 or 2
    const short8 z8 = {0, 0, 0, 0, 0, 0, 0, 0};
    short8 Bf[2];
    {
        int kq0 = quad * 8;
        Bf[0] = (kq0 < K) ? *(const short8*)&f[fpx + kq0] : z8;
        Bf[1] = (nkc > 1) ? *(const short8*)&f[fpx + 32 + quad * 8] : z8;
    }
    __syncthreads();

    // ---- per-lane tap cells: n = quad, 4+quad, 8 (for all 4 g-regs)
    const int nA = quad, nB = 4 + quad;
    const bf16* nbA = neigh_s + ((hl + nA / 3) * 10 + wl + nA % 3) * (CC + 2);
    const bf16* nbB = neigh_s + ((hl + nB / 3) * 10 + wl + nB % 3) * (CC + 2);
    const bf16* nbC = neigh_s + ((hl + 2) * 10 + wl + 2) * (CC + 2);
    const int x32 = ((lane ^ 32) & 63) << 2;        // bpermute byte index
    const bool q0 = (quad == 0);
    const bool bhi = (quad >> 1) != 0;              // q bit1 (lane bit5)
    const bool blo = (quad & 1) != 0;               // q bit0 (lane bit4)
    const bool l4 = (l16 < 4);
    bf16* osl = out_s + ((wave << 6) + lane) * (CC + 2);

    const char* pk = (const char*)kwp + (((size_t)c0 * 36 + l16) * K + quad * 8) * 2;
    const int dkc = 36 * K * 2;
    const int d16 = 16 * K * 2;
    const int d32 = 32 * K * 2;

    #pragma unroll 2
    for (int c = 0; c < CC; ++c) {
        const float* kbc = kb_s + c * 40;
        f32x4 a0 = *(const f32x4*)(kbc + (quad << 2));       // j = 4q+r
        f32x4 a1 = *(const f32x4*)(kbc + 16 + (quad << 2));  // j = 16+4q+r
        f32x4 a2 = *(const f32x4*)(kbc + 32);                // j = 32+r (q0 only)
        #pragma unroll
        for (int ch = 0; ch < 2; ++ch) {
            if (ch >= nkc) break;
            bool kok = (ch * 32 + quad * 8) < K;
            short8 f0 = kok ? *(const short8*)(pk + ch * 64) : z8;
            short8 f1 = kok ? *(const short8*)(pk + d16 + ch * 64) : z8;
            short8 f2 = (kok && l4) ? *(const short8*)(pk + d32 + ch * 64) : z8;
            a0 = __builtin_amdgcn_mfma_f32_16x16x32_bf16(f0, Bf[ch], a0, 0, 0, 0);
            a1 = __builtin_amdgcn_mfma_f32_16x16x32_bf16(f1, Bf[ch], a1, 0, 0, 0);
            a2 = __builtin_amdgcn_mfma_f32_16x16x32_bf16(f2, Bf[ch], a2, 0, 0, 0);
        }
        pk += dkc;
        float nv0 = b2f(nbA[c]), nv1 = b2f(nbB[c]), nv8 = b2f(nbC[c]);
        float Vs[4], Va[4];
        #pragma unroll
        for (int r = 0; r < 4; ++r) {
            float e0 = __expf(a0[r]);
            float e1 = __expf(a1[r]);
            float e2 = __expf(a2[r]);
            float e2m = q0 ? e2 : 0.f;
            Vs[r] = e0 + e1 + e2m;
            Va[r] = fmaf(e0, nv0, fmaf(e1, nv1, e2m * nv8));
        }
        // transpose-reduce over quads; lane ends with row r = quad.
        float sd0 = bhi ? Vs[0] : Vs[2];
        float sd1 = bhi ? Vs[1] : Vs[3];
        float sa0 = bhi ? Va[0] : Va[2];
        float sa1 = bhi ? Va[1] : Va[3];
        float rs0 = __int_as_float(__builtin_amdgcn_ds_bpermute(x32, __float_as_int(sd0)));
        float rs1 = __int_as_float(__builtin_amdgcn_ds_bpermute(x32, __float_as_int(sd1)));
        float ra0 = __int_as_float(__builtin_amdgcn_ds_bpermute(x32, __float_as_int(sa0)));
        float ra1 = __int_as_float(__builtin_amdgcn_ds_bpermute(x32, __float_as_int(sa1)));
        float Ps0 = (bhi ? Vs[2] : Vs[0]) + rs0;
        float Ps1 = (bhi ? Vs[3] : Vs[1]) + rs1;
        float Pa0 = (bhi ? Va[2] : Va[0]) + ra0;
        float Pa1 = (bhi ? Va[3] : Va[1]) + ra1;
        float ss = blo ? Ps0 : Ps1;
        float sa = blo ? Pa0 : Pa1;
        float qs = __int_as_float(__builtin_amdgcn_ds_swizzle(__float_as_int(ss), 0x401F));
        float qa = __int_as_float(__builtin_amdgcn_ds_swizzle(__float_as_int(sa), 0x401F));
        float Ss = (blo ? Ps1 : Ps0) + qs;
        float Sa = (blo ? Pa1 : Pa0) + qa;
        osl[c] = f2b(__fdividef(Sa, Ss));
    }

    __syncthreads();
    // ---- coalesced write-out: slot s = (wave, quad, hb, wl) -> (row, col)
    const size_t obase = (size_t)b * 4 * H * W;
    for (int i = tid; i < 256 * CC; i += 256) {
        int c = i % CC, s = i / CC;
        int wv = s >> 6, q = (s >> 4) & 3, hb = (s >> 3) & 1, wls = s & 7;
        int row_l = (wls << 1) + (q & 1);               // 2w + v
        int col_l = (((wv << 1) + hb) << 1) + (q >> 1); // 2h + u
        size_t P = obase + (size_t)(2 * w0 + row_l) * (2 * W) + (2 * h0 + col_l);
        out[P * C + c0 + c] = out_s[s * (CC + 2) + c];
    }
}

// ---------------------------------------------------------------- fused memory-bank + final 1x1 conv
__global__ __launch_bounds__(256, 2) void memfuse_final(
        const bf16* __restrict__ x, const void* __restrict__ memw,
        const void* __restrict__ fw, const void* __restrict__ fb,
        const float* __restrict__ flg, void* __restrict__ out, int HW) {
    __shared__ float mns[64 * 32];
    __shared__ float fws[66];
    const bool isb = (*flg != 0.f);
    if (threadIdx.x < 64) {
        int s = threadIdx.x;
        float v[32];
        float ss = 0.f;
        #pragma unroll
        for (int c = 0; c < 32; ++c) { v[c] = ldin(memw, s * 32 + c, isb); ss += v[c] * v[c]; }
        float inv = 1.f / fmaxf(sqrtf(ss), 1e-12f);
        #pragma unroll
        for (int c = 0; c < 32; ++c) mns[s * 32 + c] = v[c] * inv;
    } else if (threadIdx.x < 128) {
        int t = threadIdx.x - 64;
        fws[t] = ldin(fw, t, isb);
    } else if (threadIdx.x == 128) {
        fws[64] = ldin(fb, 0, isb);
        fws[65] = ldin(fb, 1, isb);
    }
    __syncthreads();

    int idx = blockIdx.x * blockDim.x + threadIdx.x;
    const bf16* xp = x + (size_t)idx * 32;

    float feat[32];
    float ss = 0.f;
    #pragma unroll
    for (int c = 0; c < 32; ++c) { feat[c] = b2f(xp[c]); ss += feat[c] * feat[c]; }
    float inv2 = 1.4426950408889634f / fmaxf(sqrtf(ss), 1e-12f);

    float se = 0.f;
    float racc[32];
    #pragma unroll
    for (int c = 0; c < 32; ++c) racc[c] = 0.f;

    for (int s = 0; s < 64; ++s) {
        const float* mr = mns + s * 32;
        float dot = 0.f;
        #pragma unroll
        for (int c = 0; c < 32; ++c) dot = fmaf(feat[c], mr[c], dot);
        float e = ex2(dot * inv2);
        se += e;
        #pragma unroll
        for (int c = 0; c < 32; ++c) racc[c] = fmaf(e, mr[c], racc[c]);
    }
    float rse = 1.f / se;
    float a0 = fws[64], a1 = fws[65];
    #pragma unroll
    for (int c = 0; c < 32; ++c) {
        float y = feat[c] + racc[c] * rse;
        a0 = fmaf(y, fws[c], a0);
        a1 = fmaf(y, fws[32 + c], a1);
    }
    int b = idx / HW, p = idx % HW;
    size_t i0 = (size_t)b * 2 * HW + p;
    size_t i1 = i0 + HW;
    if (isb) { ((bf16*)out)[i0] = f2b(a0); ((bf16*)out)[i1] = f2b(a1); }
    else     { ((float*)out)[i0] = a0;     ((float*)out)[i1] = a1; }
}

// ================================================================ host
extern "C" void kernel_launch(void* const* d_in, const int* in_sizes, int n_in,
                              void* d_out, int out_size, void* d_ws, size_t ws_size,
                              hipStream_t stream) {
    const void* x0_0 = d_in[0];
    const void* x1_0 = d_in[1];
    const void* x2_0 = d_in[2];
    const void* x3_0 = d_in[3];
    const void* c3_w1 = d_in[4];  const void* c3_b1 = d_in[5];  const void* c3_a1 = d_in[6];
    const void* c3_w2 = d_in[7];  const void* c3_b2 = d_in[8];  const void* c3_a2 = d_in[9];
    const void* c3_kw = d_in[10]; const void* c3_kb = d_in[11];
    const void* c2_w1 = d_in[12]; const void* c2_b1 = d_in[13]; const void* c2_a1 = d_in[14];
    const void* c2_w2 = d_in[15]; const void* c2_b2 = d_in[16]; const void* c2_a2 = d_in[17];
    const void* c2_kw = d_in[18]; const void* c2_kb = d_in[19];
    const void* c1_w1 = d_in[20]; const void* c1_b1 = d_in[21]; const void* c1_a1 = d_in[22];
    const void* c1_w2 = d_in[23]; const void* c1_b2 = d_in[24]; const void* c1_a2 = d_in[25];
    const void* c1_kw = d_in[26]; const void* c1_kb = d_in[27];
    const void* b21_w1 = d_in[28]; const void* b21_b1 = d_in[29];
    const void* b21_w2 = d_in[30]; const void* b21_b2 = d_in[31];
    const void* b12_w1 = d_in[32]; const void* b12_b1 = d_in[33];
    const void* b12_w2 = d_in[34]; const void* b12_b2 = d_in[35];
    const void* b03_w1 = d_in[36]; const void* b03_b1 = d_in[37];
    const void* b03_w2 = d_in[38]; const void* b03_b2 = d_in[39];
    const void* fin_w = d_in[40];  const void* fin_b = d_in[41];
    const void* memw  = d_in[42];
    (void)in_sizes; (void)n_in;

    const int TB = 256;
    auto blocks = [](int n) { return (n + 255) / 256; };

    const size_t NEED = 25165824 + 65536;
    if (ws_size < NEED) {
        diag_fill<<<blocks(out_size / 2), TB, 0, stream>>>(
            (unsigned int*)d_out, out_size / 2, (float)ws_size);
        return;
    }
    const size_t NEED_X0 = 25165824 + 8388608 + 65536 + 256;
    const bool have_x0cl = (ws_size >= NEED_X0);

    size_t tail = (ws_size - 65536) & ~(size_t)255;
    bf16*  wtail = (bf16*)((char*)d_ws + tail);
    float* flg   = (float*)((char*)d_ws + tail + 63488);
    char*  zstrip = (char*)d_ws + tail + 63744;     // 1 KiB zero strip

    // 24 MiB arena (12,582,912 bf16 elems), channels-last, verified live ranges.
    bf16* A = (bf16*)d_ws;
    bf16* x3up  = A + 0;         // [2,64,64,256]
    bf16* ctx3p = A + 2097152;   // [2,32,32,128]
    bf16* f3a   = A + 2359296;   // [2,32,32,128]
    bf16* f3b   = A + 2621440;   // [2,32,32,64]
    bf16* kw3p  = A + 3000000;   // 589,824 elems (free during caun3)
    bf16* t2a   = A + 2097152;   // [2,64,64,128]
    bf16* x2cl  = A + 3145728;   // [2,64,64,128]
    bf16* x2_1  = A + 0;         // [2,64,64,128]
    bf16* ctx2  = A + 1048576;   // [2,64,64,64]
    bf16* f2a   = A + 1572864;   // [2,64,64,64]
    bf16* f2b   = A + 2097152;   // [2,64,64,32]
    bf16* x2up  = A + 2359296;   // [2,128,128,128]
    bf16* t1a   = A + 0;         // [2,128,128,64]
    bf16* x1cl  = A + 6995968;   // [2,128,128,64]
    bf16* x1_2  = A + 10485760;  // [2,128,128,64]
    bf16* ctx1  = A + 4194304;   // [2,128,128,32]
    bf16* f1a   = A + 5242880;   // [2,128,128,32]
    bf16* f1b   = A + 9437184;   // [2,128,128,16]
    bf16* kw1p  = A + 8388608;   // 36,864 elems (free gap during caun1)
    bf16* x1up  = A + 0;         // [2,256,256,64]
    bf16* t0a   = A + 8388608;   // [2,256,256,32]
    bf16* x0_3  = A + 0;         // [2,256,256,32]
    bf16* wslot = A + 6553600;   // conv weight packs + caun2 kw pack
    bf16* x0cl  = A + 12582912;  // [2,256,256,32] (only if have_x0cl)

    detect_kernel<<<1, 64, 0, stream>>>((const unsigned int*)x0_0, flg, (unsigned int*)zstrip);

    auto wpk = [&](const void* w, bf16* dst, int Cout, int Cin) {
        wpack_kernel<<<blocks(Cout * Cin * 9), TB, 0, stream>>>(w, flg, dst, Cout, Cin);
    };
    auto cgN = [](int H, int W, int Cout, int RT) {
        return dim3(W >> 4, H / (4 * RT), 2 * (Cout >> 4));
    };

    if (have_x0cl)
        nchw2cl<<<2 * 1 * 1024, TB, 0, stream>>>(x0_0, flg, x0cl, 32, 65536);

    // ---- caun3: ctx = pool(x2_0) -> [2,32,32,128] cl
    pool2_cl<<<blocks(262144), TB, 0, stream>>>(x2_0, flg, ctx3p, 2, 128, 32, 32);
    wpk(c3_w1, wslot, 128, 128);
    conv3x3_lds<1><<<cgN(32, 32, 128, 1), TB, 0, stream>>>(
        nullptr, 0, ctx3p, 128, wslot, c3_b1, c3_a1, flg, zstrip, f3a, 32, 32, 128, 2);
    wpk(c3_w2, wslot, 64, 128);
    conv3x3_lds<1><<<cgN(32, 32, 64, 1), TB, 0, stream>>>(
        nullptr, 0, f3a, 128, wslot, c3_b2, c3_a2, flg, zstrip, f3b, 32, 32, 64, 2);
    b2bpack<<<blocks(256 * 36 * 64), TB, 0, stream>>>(c3_kw, flg, kw3p, 256 * 36 * 64);
    caun_v5<8><<<dim3(16, 2, 32), TB, 0, stream>>>(
        f3b, x3_0, 1, kw3p, c3_kb, flg, x3up, 256, 64, 32, 32);

    // ---- block21: cat(x2_0 -> cl [128], x3up cl[256]) -> 128 -> 128 @64x64
    nchw2cl<<<2 * 4 * 64, TB, 0, stream>>>(x2_0, flg, x2cl, 128, 4096);
    wpk(b21_w1, wslot, 128, 384);
    conv3x3_lds<1><<<cgN(64, 64, 128, 1), TB, 0, stream>>>(
        x2cl, 128, x3up, 256, wslot, b21_b1, nullptr, flg, zstrip, t2a, 64, 64, 128, 1);
    wpk(b21_w2, wslot, 128, 128);
    conv3x3_lds<1><<<cgN(64, 64, 128, 1), TB, 0, stream>>>(
        nullptr, 0, t2a, 128, wslot, b21_b2, nullptr, flg, zstrip, x2_1, 64, 64, 128, 1);

    // ---- caun2: ctx = pool(x1_0) -> [2,64,64,64] cl
    pool2_cl<<<blocks(524288), TB, 0, stream>>>(x1_0, flg, ctx2, 2, 64, 64, 64);
    wpk(c2_w1, wslot, 64, 64);
    conv3x3_lds<1><<<cgN(64, 64, 64, 1), TB, 0, stream>>>(
        nullptr, 0, ctx2, 64, wslot, c2_b1, c2_a1, flg, zstrip, f2a, 64, 64, 64, 2);
    wpk(c2_w2, wslot, 32, 64);
    conv3x3_lds<1><<<cgN(64, 64, 32, 1), TB, 0, stream>>>(
        nullptr, 0, f2a, 64, wslot, c2_b2, c2_a2, flg, zstrip, f2b, 64, 64, 32, 2);
    b2bpack<<<blocks(128 * 36 * 32), TB, 0, stream>>>(c2_kw, flg, wslot, 128 * 36 * 32);
    caun_v5<8><<<dim3(64, 2, 16), TB, 0, stream>>>(
        f2b, x2_1, 0, wslot, c2_kb, flg, x2up, 128, 32, 64, 64);

    // ---- block12: cat(x1_0 -> cl [64], x2up cl[128]) -> 64 -> 64 @128x128
    nchw2cl<<<2 * 2 * 256, TB, 0, stream>>>(x1_0, flg, x1cl, 64, 16384);
    wpk(b12_w1, wslot, 64, 192);
    conv3x3_lds<1><<<cgN(128, 128, 64, 1), TB, 0, stream>>>(
        x1cl, 64, x2up, 128, wslot, b12_b1, nullptr, flg, zstrip, t1a, 128, 128, 64, 1);
    wpk(b12_w2, wslot, 64, 64);
    conv3x3_lds<1><<<cgN(128, 128, 64, 1), TB, 0, stream>>>(
        nullptr, 0, t1a, 64, wslot, b12_b2, nullptr, flg, zstrip, x1_2, 128, 128, 64, 1);

    // ---- caun1: ctx = pool(x0_0) -> [2,128,128,32] cl
    pool2_cl<<<blocks(1048576), TB, 0, stream>>>(x0_0, flg, ctx1, 2, 32, 128, 128);
    wpk(c1_w1, wslot, 32, 32);
    conv3x3_lds<1><<<cgN(128, 128, 32, 1), TB, 0, stream>>>(
        nullptr, 0, ctx1, 32, wslot, c1_b1, c1_a1, flg, zstrip, f1a, 128, 128, 32, 2);
    wpk(c1_w2, wslot, 16, 32);
    conv3x3_lds<1><<<cgN(128, 128, 16, 1), TB, 0, stream>>>(
        nullptr, 0, f1a, 32, wslot, c1_b2, c1_a2, flg, zstrip, f1b, 128, 128, 16, 2);
    b2bpack<<<blocks(64 * 36 * 16), TB, 0, stream>>>(c1_kw, flg, kw1p, 64 * 36 * 16);
    caun_v5<8><<<dim3(256, 2, 8), TB, 0, stream>>>(
        f1b, x1_2, 0, kw1p, c1_kb, flg, x1up, 64, 16, 128, 128);

    // ---- block03: cat(x0_0 [32], x1up cl[64]) -> 32 -> 32 @256x256
    wpk(b03_w1, wtail, 32, 96);
    if (have_x0cl) {
        conv3x3_lds<1><<<cgN(256, 256, 32, 1), TB, 0, stream>>>(
            x0cl, 32, x1up, 64, wtail, b03_b1, nullptr, flg, zstrip, t0a, 256, 256, 32, 1);
    } else {
        conv3x3_ext<4><<<dim3(16, 16, 4), TB, 0, stream>>>(
            x0_0, 32, x1up, 64, wtail, b03_b1, nullptr, flg, t0a, 256, 256, 32, 1);
    }
    wpk(b03_w2, wtail, 32, 32);
    conv3x3_lds<1><<<cgN(256, 256, 32, 1), TB, 0, stream>>>(
        nullptr, 0, t0a, 32, wtail, b03_b2, nullptr, flg, zstrip, x0_3, 256, 256, 32, 1);

    // ---- fused memory-bank residual + final 1x1 conv -> [2,2,256,256]
    memfuse_final<<<512, TB, 0, stream>>>(x0_3, memw, fin_w, fin_b, flg, d_out, 256 * 256);
}

// Round 13
// 435.160 us; speedup vs baseline: 1.0353x; 1.0353x over previous
//
#include <hip/hip_runtime.h>
#include <hip/hip_bf16.h>
#include <math.h>

typedef __hip_bfloat16 bf16;
typedef short short8 __attribute__((ext_vector_type(8)));   // bf16x8 MFMA frag (4 VGPRs)
typedef float f32x4 __attribute__((ext_vector_type(4)));    // MFMA accumulator
typedef unsigned short us4 __attribute__((ext_vector_type(4)));

static __device__ __forceinline__ float b2f(bf16 x) { return __bfloat162float(x); }
static __device__ __forceinline__ bf16  f2b(float x) { return __float2bfloat16(x); }
static __device__ __forceinline__ short f2bs(float x) { bf16 t = f2b(x); return *reinterpret_cast<short*>(&t); }
static __device__ __forceinline__ float ex2(float x) { float r; asm("v_exp_f32 %0, %1" : "=v"(r) : "v"(x)); return r; }

// Polymorphic input load: isb=true -> bf16 storage, else f32 storage.
static __device__ __forceinline__ float ldin(const void* p, size_t i, bool isb) {
    return isb ? b2f(((const bf16*)p)[i]) : ((const float*)p)[i];
}

// ---------------------------------------------------------------- dtype detect (+ zero strip fill)
__global__ void detect_kernel(const unsigned int* __restrict__ x, float* __restrict__ flagp,
                              unsigned int* __restrict__ zstrip) {
    __shared__ int sh[64];
    for (int i = threadIdx.x; i < 256; i += 64) zstrip[i] = 0u;
    int insane = 0;
    for (int i = threadIdx.x; i < 1024; i += 64) {
        unsigned int lo = (x[i] & 0xFFFFu) << 16;
        float v = __uint_as_float(lo);
        if (!(fabsf(v) <= 1e6f)) insane++;
    }
    sh[threadIdx.x] = insane;
    __syncthreads();
    if (threadIdx.x == 0) {
        int t = 0;
        for (int i = 0; i < 64; ++i) t += sh[i];
        *flagp = (t < 16) ? 1.f : 0.f;            // 1 => inputs are bf16
    }
}

// ---------------------------------------------------------------- diagnostic fill
__global__ void diag_fill(unsigned int* __restrict__ out, int nwords, float val) {
    int i = blockIdx.x * blockDim.x + threadIdx.x;
    if (i < nwords) {
        unsigned short h = (unsigned short)(__float_as_uint(val) >> 16);
        out[i] = ((unsigned int)h << 16) | h;
    }
}

// ---------------------------------------------------------------- weight pack: [co][ci][tap] -> [tap][co][ci] bf16
__global__ void wpack_kernel(const void* __restrict__ wt, const float* __restrict__ flg,
                             bf16* __restrict__ dst, int Cout, int Cin) {
    bool isb = (*flg != 0.f);
    int n = Cout * Cin * 9;
    int idx = blockIdx.x * blockDim.x + threadIdx.x;
    if (idx >= n) return;
    int ci = idx % Cin;
    int co = (idx / Cin) % Cout;
    int tap = idx / (Cin * Cout);
    dst[idx] = f2b(ldin(wt, ((size_t)co * Cin + ci) * 9 + tap, isb));
}

// ---------------------------------------------------------------- flat convert to bf16 (caun kw pack)
__global__ void b2bpack(const void* __restrict__ src, const float* __restrict__ flg,
                        bf16* __restrict__ dst, int n) {
    bool isb = (*flg != 0.f);
    int i = blockIdx.x * blockDim.x + threadIdx.x;
    if (i < n) dst[i] = f2b(ldin(src, i, isb));
}

// ---------------------------------------------------------------- NCHW ext -> channels-last bf16 (LDS tile transpose)
__global__ void nchw2cl(const void* __restrict__ in, const float* __restrict__ flg,
                        bf16* __restrict__ out, int C, int HW) {
    __shared__ bf16 t[32][72];
    bool isb = (*flg != 0.f);
    int npx = HW >> 6, nc = C >> 5;
    int blk = blockIdx.x;
    int px0 = (blk % npx) << 6;
    int c0  = ((blk / npx) % nc) << 5;
    int b   = blk / (npx * nc);
    if (isb) {
        const bf16* pin = (const bf16*)in;
        for (int i = threadIdx.x; i < 512; i += 256) {
            int px4 = (i & 15) << 2, c = i >> 4;
            *(us4*)&t[c][px4] =
                *(const us4*)(pin + ((size_t)(b * C + c0 + c)) * HW + px0 + px4);
        }
    } else {
        const float* pf = (const float*)in;
        for (int i = threadIdx.x; i < 512; i += 256) {
            int px4 = (i & 15) << 2, c = i >> 4;
            float4 v = *(const float4*)(pf + ((size_t)(b * C + c0 + c)) * HW + px0 + px4);
            t[c][px4 + 0] = f2b(v.x);
            t[c][px4 + 1] = f2b(v.y);
            t[c][px4 + 2] = f2b(v.z);
            t[c][px4 + 3] = f2b(v.w);
        }
    }
    __syncthreads();
    for (int i = threadIdx.x; i < 512; i += 256) {
        int px = i >> 3, c4 = (i & 7) << 2;
        us4 v;
        v[0] = *(const unsigned short*)&t[c4 + 0][px];
        v[1] = *(const unsigned short*)&t[c4 + 1][px];
        v[2] = *(const unsigned short*)&t[c4 + 2][px];
        v[3] = *(const unsigned short*)&t[c4 + 3][px];
        *(us4*)&out[((size_t)b * HW + px0 + px) * C + c0 + c4] = v;
    }
}

// ---------------------------------------------------------------- 2x2 mean pool: NCHW ext -> channels-last bf16 ws
__global__ void pool2_cl(const void* __restrict__ in, const float* __restrict__ flg,
                         bf16* __restrict__ out, int B, int C, int H2, int W2) {
    bool isb = (*flg != 0.f);
    int idx = blockIdx.x * blockDim.x + threadIdx.x;
    int total = B * H2 * W2 * C;
    if (idx >= total) return;
    int c = idx % C;
    int pix = idx / C;
    int w = pix % W2;
    int h = (pix / W2) % H2;
    int b = pix / (W2 * H2);
    int H = H2 * 2, W = W2 * 2;
    size_t base = ((size_t)(b * C + c)) * H * W + (size_t)(2 * h) * W + 2 * w;
    float s;
    if (isb) {
        const bf16* pin = (const bf16*)in;
        unsigned int a = *(const unsigned int*)(pin + base);
        unsigned int d = *(const unsigned int*)(pin + base + W);
        float v00 = __uint_as_float(a << 16);
        float v01 = __uint_as_float(a & 0xFFFF0000u);
        float v10 = __uint_as_float(d << 16);
        float v11 = __uint_as_float(d & 0xFFFF0000u);
        s = v00 + v01 + v10 + v11;
    } else {
        const float* pf = (const float*)in;
        float2 r0 = *(const float2*)(pf + base);
        float2 r1 = *(const float2*)(pf + base + W);
        s = r0.x + r0.y + r1.x + r1.y;
    }
    out[idx] = f2b(0.25f * s);
}

// ---------------------------------------------------------------- MFMA conv3x3, LDS-staged, double-buffered
// Round-25: r11 config reverted (best, 445.4us). NEW: WS1 template flag for
// big convs -- single-buffered w_s (weights 10.4KB) with 2-barrier chunk
// schedule: LDS 46.7->36.3KB at RT=2 -> 4 blocks/CU (vs 3). Ordering kept:
// issue(ic+1) ahead of compute; commit_in waits only older rin (rwt stays in
// flight); commit_w between barriers. WS1=0 path byte-identical to proven r11.
template<int RT, int WS1>
__global__ __launch_bounds__(256) void conv3x3_lds(
        const bf16* __restrict__ in1, int C1,
        const bf16* __restrict__ in2, int C2,
        const bf16* __restrict__ wp,
        const void* __restrict__ bias,
        const void* __restrict__ alpha,
        const float* __restrict__ flg,
        const char* __restrict__ zs,
        bf16* __restrict__ out,
        int H, int W, int Cout, int act) {
    constexpr int NRB = 4 * RT + 2;            // staged rows
    constexpr int NIU = NRB * 18 * 4;          // input 16B units
    constexpr int KI = (NIU + 255) / 256;
    constexpr int KW = 3;                      // 576 weight units / 256
    constexpr int NWB = WS1 ? 1 : 2;
    __shared__ bf16 in_s[2][NRB][18][36];      // [buf][row][px][ci pad 32->36]
    __shared__ bf16 w_s[NWB][9][16][36];       // [buf][tap][cout][ci pad]

    const bool isb = (*flg != 0.f);
    const int Cin = C1 + C2;
    const int tid = threadIdx.x;
    const int lane = tid & 63, wave = tid >> 6;
    const int quad = lane >> 4, l16 = lane & 15;
    const int cot = Cout >> 4;
    const int b = blockIdx.z / cot;
    const int co_base = (blockIdx.z % cot) << 4;
    const int r0b = blockIdx.y * (4 * RT);
    const int c0 = blockIdx.x << 4;
    const int cog = co_base + l16;

    // ---- chunk-invariant per-thread staging addresses
    const char* pin1[KI];
    const char* pin2[KI];
    #pragma unroll
    for (int k = 0; k < KI; ++k) {
        int u = min(tid + k * 256, NIU - 1);
        int sub = u & 3, px = (u >> 2) % 18, row = (u >> 2) / 18;
        int ih = r0b + row - 1, iw = c0 + px - 1;
        bool ok = (ih >= 0) && (ih < H) && (iw >= 0) && (iw < W);
        int ihc = min(max(ih, 0), H - 1), iwc = min(max(iw, 0), W - 1);
        size_t pix = (size_t)(b * H + ihc) * W + iwc;
        pin1[k] = (ok && C1 > 0) ? (const char*)(in1 + pix * C1 + sub * 8) : (zs + sub * 16);
        pin2[k] = ok ? (const char*)(in2 + pix * C2 + sub * 8) : (zs + sub * 16);
    }
    size_t offw[KW];
    #pragma unroll
    for (int k = 0; k < KW; ++k) {
        int u = min(tid + k * 256, 575);
        int sub = u & 3, cw = (u >> 2) & 15, tap = u >> 6;
        offw[k] = ((size_t)(tap * Cout + co_base + cw) * Cin + sub * 8) * 2;
    }
    const char* pw = (const char*)wp;

    short8 rin[KI], rwt[KW];
    auto issue = [&](int ci0) {
        const bool f1 = ci0 < C1;
        const int cl2 = (f1 ? ci0 : ci0 - C1) * 2;
        #pragma unroll
        for (int k = 0; k < KI; ++k)
            rin[k] = *(const short8*)((f1 ? pin1[k] : pin2[k]) + cl2);
        #pragma unroll
        for (int k = 0; k < KW; ++k)
            rwt[k] = *(const short8*)(pw + offw[k] + (size_t)ci0 * 2);
    };
    auto commit_in = [&](int bufi) {
        #pragma unroll
        for (int k = 0; k < KI; ++k) {
            int u = tid + k * 256;
            if (u < NIU) {
                int sub = u & 3, px = (u >> 2) % 18, row = (u >> 2) / 18;
                *(short8*)&in_s[bufi][row][px][sub * 8] = rin[k];
            }
        }
    };
    auto commit_w = [&](int bufi) {
        #pragma unroll
        for (int k = 0; k < KW; ++k) {
            int u = tid + k * 256;
            if (u < 576) {
                int sub = u & 3, cw = (u >> 2) & 15, tap = u >> 6;
                *(short8*)&w_s[bufi][tap][cw][sub * 8] = rwt[k];
            }
        }
    };

    float bv = ldin(bias, cog, isb);
    f32x4 acc[RT];
    #pragma unroll
    for (int t = 0; t < RT; ++t) acc[t] = {bv, bv, bv, bv};

    const int nchunk = Cin >> 5;
    issue(0);
    commit_in(0);
    commit_w(0);
    __syncthreads();
    int buf = 0;
    for (int ic = 0; ic < nchunk; ++ic) {
        const bool nx = (ic + 1 < nchunk);
        if (nx) issue((ic + 1) << 5);           // loads in flight over compute
        const int wbuf = WS1 ? 0 : buf;
        #pragma unroll
        for (int kw = 0; kw < 3; ++kw) {
            short8 F[RT + 2];
            #pragma unroll
            for (int j = 0; j < RT + 2; ++j)
                F[j] = *(const short8*)&in_s[buf][wave * RT + j][l16 + kw][quad * 8];
            #pragma unroll
            for (int kh = 0; kh < 3; ++kh) {
                short8 Wk = *(const short8*)&w_s[wbuf][kh * 3 + kw][l16][quad * 8];
                #pragma unroll
                for (int t = 0; t < RT; ++t)
                    acc[t] = __builtin_amdgcn_mfma_f32_16x16x32_bf16(F[t + kh], Wk, acc[t], 0, 0, 0);
            }
        }
        if (WS1) {
            if (nx) commit_in(buf ^ 1);         // waits rin only; rwt stays in flight
            __syncthreads();                    // all waves done reading w_s[0]
            if (nx) commit_w(0);                // weights for ic+1
            __syncthreads();                    // visible
        } else {
            if (nx) { commit_in(buf ^ 1); commit_w(buf ^ 1); }
            __syncthreads();
        }
        buf ^= 1;
    }

    float a = (act == 2) ? ldin(alpha, cog, isb) : 0.f;
    const int r0 = r0b + wave * RT;
    #pragma unroll
    for (int t = 0; t < RT; ++t) {
        #pragma unroll
        for (int reg = 0; reg < 4; ++reg) {
            float v = acc[t][reg];
            if (act == 1) v = fmaxf(v, 0.f);
            else if (act == 2) v = (v >= 0.f) ? v : a * v;
            out[(((size_t)(b * H) + r0 + t) * W + c0 + (quad << 2) + reg) * Cout + cog] = f2b(v);
        }
    }
}

// ---------------------------------------------------------------- MFMA conv3x3, ext-NCHW fallback
template<int RT>
__global__ __launch_bounds__(256) void conv3x3_ext(
        const void* __restrict__ in1, int C1,
        const bf16* __restrict__ in2, int C2,
        const bf16* __restrict__ wp,
        const void* __restrict__ bias,
        const void* __restrict__ alpha,
        const float* __restrict__ flg,
        bf16* __restrict__ out,
        int H, int W, int Cout, int act) {
    const bool isb = (*flg != 0.f);
    const int Cin = C1 + C2;
    const int lane = threadIdx.x & 63;
    const int wave = threadIdx.x >> 6;
    const int quad = lane >> 4, l16 = lane & 15;
    const int cot = Cout >> 4;
    const int b = blockIdx.z / cot;
    const int co_base = (blockIdx.z % cot) << 4;
    const int r0 = (blockIdx.y * 4 + wave) * RT;
    const int c0 = blockIdx.x << 4;
    const int cog = co_base + l16;

    float bv = ldin(bias, cog, isb);
    f32x4 acc[RT];
    #pragma unroll
    for (int t = 0; t < RT; ++t) acc[t] = {bv, bv, bv, bv};

    for (int ci0 = 0; ci0 < Cin; ci0 += 32) {
        const bool from1 = (ci0 < C1);
        #pragma unroll
        for (int kw = 0; kw < 3; ++kw) {
            const int iw = c0 + l16 + kw - 1;
            const bool okc = (iw >= 0) && (iw < W);
            short8 F[RT + 2];
            #pragma unroll
            for (int j = 0; j < RT + 2; ++j) {
                const int ih = r0 + j - 1;
                const bool ok = okc && (ih >= 0) && (ih < H);
                F[j] = short8{0, 0, 0, 0, 0, 0, 0, 0};
                if (from1) {
                    if (ok) {
                        size_t base = ((size_t)(b * C1 + ci0 + quad * 8)) * H * W
                                    + (size_t)ih * W + iw;
                        #pragma unroll
                        for (int jj = 0; jj < 8; ++jj)
                            F[j][jj] = f2bs(ldin(in1, base + (size_t)jj * H * W, isb));
                    }
                } else {
                    if (ok)
                        F[j] = *(const short8*)&in2[(((size_t)(b * H) + ih) * W + iw) * C2
                                                     + (ci0 - C1) + quad * 8];
                }
            }
            #pragma unroll
            for (int kh = 0; kh < 3; ++kh) {
                short8 bfrag = *(const short8*)&wp[((size_t)(kh * 3 + kw) * Cout + cog) * Cin
                                                   + ci0 + quad * 8];
                #pragma unroll
                for (int t = 0; t < RT; ++t)
                    acc[t] = __builtin_amdgcn_mfma_f32_16x16x32_bf16(F[t + kh], bfrag, acc[t], 0, 0, 0);
            }
        }
    }

    float a = (act == 2) ? ldin(alpha, cog, isb) : 0.f;
    #pragma unroll
    for (int t = 0; t < RT; ++t) {
        #pragma unroll
        for (int reg = 0; reg < 4; ++reg) {
            float v = acc[t][reg];
            if (act == 1) v = fmaxf(v, 0.f);
            else if (act == 2) v = (v >= 0.f) ? v : a * v;
            out[(((size_t)(b * H) + r0 + t) * W + c0 + (quad << 2) + reg) * Cout + cog] = f2b(v);
        }
    }
}

// ---------------------------------------------------------------- CAUN v5 (CC=8): unchanged (anchor)
template<int CC>
__global__ __launch_bounds__(256) void caun_v5(
        const bf16* __restrict__ f,
        const void* __restrict__ xlow, int xext,
        const bf16* __restrict__ kwp,
        const void* __restrict__ kb,
        const float* __restrict__ flg,
        bf16* __restrict__ out,
        int C, int K, int H, int W) {
    __shared__ float kb_s[CC * 40];             // [c][36 pad 40]
    __shared__ bf16  neigh_s[100 * (CC + 2)];   // [cell][c pad]
    __shared__ bf16  out_s[256 * (CC + 2)];     // [slot][c pad]

    const bool isb = (*flg != 0.f);
    const int tw = W >> 3;
    const int h0 = (blockIdx.x / tw) << 3;
    const int w0 = (blockIdx.x % tw) << 3;
    const int b  = blockIdx.y;
    const int c0 = blockIdx.z * CC;
    const int tid = threadIdx.x, wave = tid >> 6, lane = tid & 63;
    const int quad = lane >> 4, l16 = lane & 15;

    // ---- stage clamped neighbor halo (c-contiguous loads)
    for (int i = tid; i < 100 * CC; i += 256) {
        int c = i % CC, cell = i / CC;
        int r = cell / 10, q = cell % 10;
        int ih = min(max(h0 + r - 1, 0), H - 1);
        int iw = min(max(w0 + q - 1, 0), W - 1);
        float v = xext
            ? ldin(xlow, ((size_t)(b * C + c0 + c)) * H * W + (size_t)ih * W + iw, isb)
            : b2f(((const bf16*)xlow)[(((size_t)(b * H) + ih) * W + iw) * C + c0 + c]);
        neigh_s[cell * (CC + 2) + c] = f2b(v);
    }
    // ---- stage bias chunk, [c][j] layout (j-contiguous global reads)
    for (int i = tid; i < 36 * CC; i += 256) {
        int j = i % 36, c = i / 36;
        kb_s[c * 40 + j] = ldin(kb, (size_t)(c0 + c) * 36 + j, isb);
    }

    // ---- hoist B-frags (f) for this wave's 16 px (2 input rows x 8 cols)
    const int hl = (wave << 1) + (l16 >> 3);
    const int wl = l16 & 7;
    const size_t fpx = ((size_t)b * H * W + (size_t)(h0 + hl) * W + (w0 + wl)) * K;
    const int nkc = ((K + 31) & ~31) >> 5;          // 1 or 2
    const short8 z8 = {0, 0, 0, 0, 0, 0, 0, 0};
    short8 Bf[2];
    {
        int kq0 = quad * 8;
        Bf[0] = (kq0 < K) ? *(const short8*)&f[fpx + kq0] : z8;
        Bf[1] = (nkc > 1) ? *(const short8*)&f[fpx + 32 + quad * 8] : z8;
    }
    __syncthreads();

    // ---- per-lane tap cells: n = quad, 4+quad, 8 (for all 4 g-regs)
    const int nA = quad, nB = 4 + quad;
    const bf16* nbA = neigh_s + ((hl + nA / 3) * 10 + wl + nA % 3) * (CC + 2);
    const bf16* nbB = neigh_s + ((hl + nB / 3) * 10 + wl + nB % 3) * (CC + 2);
    const bf16* nbC = neigh_s + ((hl + 2) * 10 + wl + 2) * (CC + 2);
    const int x32 = ((lane ^ 32) & 63) << 2;        // bpermute byte index
    const bool q0 = (quad == 0);
    const bool bhi = (quad >> 1) != 0;              // q bit1 (lane bit5)
    const bool blo = (quad & 1) != 0;               // q bit0 (lane bit4)
    const bool l4 = (l16 < 4);
    bf16* osl = out_s + ((wave << 6) + lane) * (CC + 2);

    const char* pk = (const char*)kwp + (((size_t)c0 * 36 + l16) * K + quad * 8) * 2;
    const int dkc = 36 * K * 2;
    const int d16 = 16 * K * 2;
    const int d32 = 32 * K * 2;

    #pragma unroll 2
    for (int c = 0; c < CC; ++c) {
        const float* kbc = kb_s + c * 40;
        f32x4 a0 = *(const f32x4*)(kbc + (quad << 2));       // j = 4q+r
        f32x4 a1 = *(const f32x4*)(kbc + 16 + (quad << 2));  // j = 16+4q+r
        f32x4 a2 = *(const f32x4*)(kbc + 32);                // j = 32+r (q0 only)
        #pragma unroll
        for (int ch = 0; ch < 2; ++ch) {
            if (ch >= nkc) break;
            bool kok = (ch * 32 + quad * 8) < K;
            short8 f0 = kok ? *(const short8*)(pk + ch * 64) : z8;
            short8 f1 = kok ? *(const short8*)(pk + d16 + ch * 64) : z8;
            short8 f2 = (kok && l4) ? *(const short8*)(pk + d32 + ch * 64) : z8;
            a0 = __builtin_amdgcn_mfma_f32_16x16x32_bf16(f0, Bf[ch], a0, 0, 0, 0);
            a1 = __builtin_amdgcn_mfma_f32_16x16x32_bf16(f1, Bf[ch], a1, 0, 0, 0);
            a2 = __builtin_amdgcn_mfma_f32_16x16x32_bf16(f2, Bf[ch], a2, 0, 0, 0);
        }
        pk += dkc;
        float nv0 = b2f(nbA[c]), nv1 = b2f(nbB[c]), nv8 = b2f(nbC[c]);
        float Vs[4], Va[4];
        #pragma unroll
        for (int r = 0; r < 4; ++r) {
            float e0 = __expf(a0[r]);
            float e1 = __expf(a1[r]);
            float e2 = __expf(a2[r]);
            float e2m = q0 ? e2 : 0.f;
            Vs[r] = e0 + e1 + e2m;
            Va[r] = fmaf(e0, nv0, fmaf(e1, nv1, e2m * nv8));
        }
        // transpose-reduce over quads; lane ends with row r = quad.
        float sd0 = bhi ? Vs[0] : Vs[2];
        float sd1 = bhi ? Vs[1] : Vs[3];
        float sa0 = bhi ? Va[0] : Va[2];
        float sa1 = bhi ? Va[1] : Va[3];
        float rs0 = __int_as_float(__builtin_amdgcn_ds_bpermute(x32, __float_as_int(sd0)));
        float rs1 = __int_as_float(__builtin_amdgcn_ds_bpermute(x32, __float_as_int(sd1)));
        float ra0 = __int_as_float(__builtin_amdgcn_ds_bpermute(x32, __float_as_int(sa0)));
        float ra1 = __int_as_float(__builtin_amdgcn_ds_bpermute(x32, __float_as_int(sa1)));
        float Ps0 = (bhi ? Vs[2] : Vs[0]) + rs0;
        float Ps1 = (bhi ? Vs[3] : Vs[1]) + rs1;
        float Pa0 = (bhi ? Va[2] : Va[0]) + ra0;
        float Pa1 = (bhi ? Va[3] : Va[1]) + ra1;
        float ss = blo ? Ps0 : Ps1;
        float sa = blo ? Pa0 : Pa1;
        float qs = __int_as_float(__builtin_amdgcn_ds_swizzle(__float_as_int(ss), 0x401F));
        float qa = __int_as_float(__builtin_amdgcn_ds_swizzle(__float_as_int(sa), 0x401F));
        float Ss = (blo ? Ps1 : Ps0) + qs;
        float Sa = (blo ? Pa1 : Pa0) + qa;
        osl[c] = f2b(__fdividef(Sa, Ss));
    }

    __syncthreads();
    // ---- coalesced write-out: slot s = (wave, quad, hb, wl) -> (row, col)
    const size_t obase = (size_t)b * 4 * H * W;
    for (int i = tid; i < 256 * CC; i += 256) {
        int c = i % CC, s = i / CC;
        int wv = s >> 6, q = (s >> 4) & 3, hb = (s >> 3) & 1, wls = s & 7;
        int row_l = (wls << 1) + (q & 1);               // 2w + v
        int col_l = (((wv << 1) + hb) << 1) + (q >> 1); // 2h + u
        size_t P = obase + (size_t)(2 * w0 + row_l) * (2 * W) + (2 * h0 + col_l);
        out[P * C + c0 + c] = out_s[s * (CC + 2) + c];
    }
}

// ---------------------------------------------------------------- fused memory-bank + final 1x1 conv
__global__ __launch_bounds__(256, 2) void memfuse_final(
        const bf16* __restrict__ x, const void* __restrict__ memw,
        const void* __restrict__ fw, const void* __restrict__ fb,
        const float* __restrict__ flg, void* __restrict__ out, int HW) {
    __shared__ float mns[64 * 32];
    __shared__ float fws[66];
    const bool isb = (*flg != 0.f);
    if (threadIdx.x < 64) {
        int s = threadIdx.x;
        float v[32];
        float ss = 0.f;
        #pragma unroll
        for (int c = 0; c < 32; ++c) { v[c] = ldin(memw, s * 32 + c, isb); ss += v[c] * v[c]; }
        float inv = 1.f / fmaxf(sqrtf(ss), 1e-12f);
        #pragma unroll
        for (int c = 0; c < 32; ++c) mns[s * 32 + c] = v[c] * inv;
    } else if (threadIdx.x < 128) {
        int t = threadIdx.x - 64;
        fws[t] = ldin(fw, t, isb);
    } else if (threadIdx.x == 128) {
        fws[64] = ldin(fb, 0, isb);
        fws[65] = ldin(fb, 1, isb);
    }
    __syncthreads();

    int idx = blockIdx.x * blockDim.x + threadIdx.x;
    const bf16* xp = x + (size_t)idx * 32;

    float feat[32];
    float ss = 0.f;
    #pragma unroll
    for (int c = 0; c < 32; ++c) { feat[c] = b2f(xp[c]); ss += feat[c] * feat[c]; }
    float inv2 = 1.4426950408889634f / fmaxf(sqrtf(ss), 1e-12f);

    float se = 0.f;
    float racc[32];
    #pragma unroll
    for (int c = 0; c < 32; ++c) racc[c] = 0.f;

    for (int s = 0; s < 64; ++s) {
        const float* mr = mns + s * 32;
        float dot = 0.f;
        #pragma unroll
        for (int c = 0; c < 32; ++c) dot = fmaf(feat[c], mr[c], dot);
        float e = ex2(dot * inv2);
        se += e;
        #pragma unroll
        for (int c = 0; c < 32; ++c) racc[c] = fmaf(e, mr[c], racc[c]);
    }
    float rse = 1.f / se;
    float a0 = fws[64], a1 = fws[65];
    #pragma unroll
    for (int c = 0; c < 32; ++c) {
        float y = feat[c] + racc[c] * rse;
        a0 = fmaf(y, fws[c], a0);
        a1 = fmaf(y, fws[32 + c], a1);
    }
    int b = idx / HW, p = idx % HW;
    size_t i0 = (size_t)b * 2 * HW + p;
    size_t i1 = i0 + HW;
    if (isb) { ((bf16*)out)[i0] = f2b(a0); ((bf16*)out)[i1] = f2b(a1); }
    else     { ((float*)out)[i0] = a0;     ((float*)out)[i1] = a1; }
}

// ================================================================ host
extern "C" void kernel_launch(void* const* d_in, const int* in_sizes, int n_in,
                              void* d_out, int out_size, void* d_ws, size_t ws_size,
                              hipStream_t stream) {
    const void* x0_0 = d_in[0];
    const void* x1_0 = d_in[1];
    const void* x2_0 = d_in[2];
    const void* x3_0 = d_in[3];
    const void* c3_w1 = d_in[4];  const void* c3_b1 = d_in[5];  const void* c3_a1 = d_in[6];
    const void* c3_w2 = d_in[7];  const void* c3_b2 = d_in[8];  const void* c3_a2 = d_in[9];
    const void* c3_kw = d_in[10]; const void* c3_kb = d_in[11];
    const void* c2_w1 = d_in[12]; const void* c2_b1 = d_in[13]; const void* c2_a1 = d_in[14];
    const void* c2_w2 = d_in[15]; const void* c2_b2 = d_in[16]; const void* c2_a2 = d_in[17];
    const void* c2_kw = d_in[18]; const void* c2_kb = d_in[19];
    const void* c1_w1 = d_in[20]; const void* c1_b1 = d_in[21]; const void* c1_a1 = d_in[22];
    const void* c1_w2 = d_in[23]; const void* c1_b2 = d_in[24]; const void* c1_a2 = d_in[25];
    const void* c1_kw = d_in[26]; const void* c1_kb = d_in[27];
    const void* b21_w1 = d_in[28]; const void* b21_b1 = d_in[29];
    const void* b21_w2 = d_in[30]; const void* b21_b2 = d_in[31];
    const void* b12_w1 = d_in[32]; const void* b12_b1 = d_in[33];
    const void* b12_w2 = d_in[34]; const void* b12_b2 = d_in[35];
    const void* b03_w1 = d_in[36]; const void* b03_b1 = d_in[37];
    const void* b03_w2 = d_in[38]; const void* b03_b2 = d_in[39];
    const void* fin_w = d_in[40];  const void* fin_b = d_in[41];
    const void* memw  = d_in[42];
    (void)in_sizes; (void)n_in;

    const int TB = 256;
    auto blocks = [](int n) { return (n + 255) / 256; };

    const size_t NEED = 25165824 + 65536;
    if (ws_size < NEED) {
        diag_fill<<<blocks(out_size / 2), TB, 0, stream>>>(
            (unsigned int*)d_out, out_size / 2, (float)ws_size);
        return;
    }
    const size_t NEED_X0 = 25165824 + 8388608 + 65536 + 256;
    const bool have_x0cl = (ws_size >= NEED_X0);

    size_t tail = (ws_size - 65536) & ~(size_t)255;
    bf16*  wtail = (bf16*)((char*)d_ws + tail);
    float* flg   = (float*)((char*)d_ws + tail + 63488);
    char*  zstrip = (char*)d_ws + tail + 63744;     // 1 KiB zero strip

    // 24 MiB arena (12,582,912 bf16 elems), channels-last, verified live ranges.
    bf16* A = (bf16*)d_ws;
    bf16* x3up  = A + 0;         // [2,64,64,256]
    bf16* ctx3p = A + 2097152;   // [2,32,32,128]
    bf16* f3a   = A + 2359296;   // [2,32,32,128]
    bf16* f3b   = A + 2621440;   // [2,32,32,64]
    bf16* kw3p  = A + 3000000;   // 589,824 elems (free during caun3)
    bf16* t2a   = A + 2097152;   // [2,64,64,128]
    bf16* x2cl  = A + 3145728;   // [2,64,64,128]
    bf16* x2_1  = A + 0;         // [2,64,64,128]
    bf16* ctx2  = A + 1048576;   // [2,64,64,64]
    bf16* f2a   = A + 1572864;   // [2,64,64,64]
    bf16* f2b   = A + 2097152;   // [2,64,64,32]
    bf16* x2up  = A + 2359296;   // [2,128,128,128]
    bf16* t1a   = A + 0;         // [2,128,128,64]
    bf16* x1cl  = A + 6995968;   // [2,128,128,64]
    bf16* x1_2  = A + 10485760;  // [2,128,128,64]
    bf16* ctx1  = A + 4194304;   // [2,128,128,32]
    bf16* f1a   = A + 5242880;   // [2,128,128,32]
    bf16* f1b   = A + 9437184;   // [2,128,128,16]
    bf16* kw1p  = A + 8388608;   // 36,864 elems (free gap during caun1)
    bf16* x1up  = A + 0;         // [2,256,256,64]
    bf16* t0a   = A + 8388608;   // [2,256,256,32]
    bf16* x0_3  = A + 0;         // [2,256,256,32]
    bf16* wslot = A + 6553600;   // conv weight packs + caun2 kw pack
    bf16* x0cl  = A + 12582912;  // [2,256,256,32] (only if have_x0cl)

    detect_kernel<<<1, 64, 0, stream>>>((const unsigned int*)x0_0, flg, (unsigned int*)zstrip);

    auto wpk = [&](const void* w, bf16* dst, int Cout, int Cin) {
        wpack_kernel<<<blocks(Cout * Cin * 9), TB, 0, stream>>>(w, flg, dst, Cout, Cin);
    };
    auto cgN = [](int H, int W, int Cout, int RT) {
        return dim3(W >> 4, H / (4 * RT), 2 * (Cout >> 4));
    };

    if (have_x0cl)
        nchw2cl<<<2 * 1 * 1024, TB, 0, stream>>>(x0_0, flg, x0cl, 32, 65536);

    // ---- caun3: ctx = pool(x2_0) -> [2,32,32,128] cl
    pool2_cl<<<blocks(262144), TB, 0, stream>>>(x2_0, flg, ctx3p, 2, 128, 32, 32);
    wpk(c3_w1, wslot, 128, 128);
    conv3x3_lds<1, 0><<<cgN(32, 32, 128, 1), TB, 0, stream>>>(
        nullptr, 0, ctx3p, 128, wslot, c3_b1, c3_a1, flg, zstrip, f3a, 32, 32, 128, 2);
    wpk(c3_w2, wslot, 64, 128);
    conv3x3_lds<1, 0><<<cgN(32, 32, 64, 1), TB, 0, stream>>>(
        nullptr, 0, f3a, 128, wslot, c3_b2, c3_a2, flg, zstrip, f3b, 32, 32, 64, 2);
    b2bpack<<<blocks(256 * 36 * 64), TB, 0, stream>>>(c3_kw, flg, kw3p, 256 * 36 * 64);
    caun_v5<8><<<dim3(16, 2, 32), TB, 0, stream>>>(
        f3b, x3_0, 1, kw3p, c3_kb, flg, x3up, 256, 64, 32, 32);

    // ---- block21: cat(x2_0 -> cl [128], x3up cl[256]) -> 128 -> 128 @64x64
    nchw2cl<<<2 * 4 * 64, TB, 0, stream>>>(x2_0, flg, x2cl, 128, 4096);
    wpk(b21_w1, wslot, 128, 384);
    conv3x3_lds<1, 0><<<cgN(64, 64, 128, 1), TB, 0, stream>>>(
        x2cl, 128, x3up, 256, wslot, b21_b1, nullptr, flg, zstrip, t2a, 64, 64, 128, 1);
    wpk(b21_w2, wslot, 128, 128);
    conv3x3_lds<1, 0><<<cgN(64, 64, 128, 1), TB, 0, stream>>>(
        nullptr, 0, t2a, 128, wslot, b21_b2, nullptr, flg, zstrip, x2_1, 64, 64, 128, 1);

    // ---- caun2: ctx = pool(x1_0) -> [2,64,64,64] cl
    pool2_cl<<<blocks(524288), TB, 0, stream>>>(x1_0, flg, ctx2, 2, 64, 64, 64);
    wpk(c2_w1, wslot, 64, 64);
    conv3x3_lds<1, 0><<<cgN(64, 64, 64, 1), TB, 0, stream>>>(
        nullptr, 0, ctx2, 64, wslot, c2_b1, c2_a1, flg, zstrip, f2a, 64, 64, 64, 2);
    wpk(c2_w2, wslot, 32, 64);
    conv3x3_lds<1, 0><<<cgN(64, 64, 32, 1), TB, 0, stream>>>(
        nullptr, 0, f2a, 64, wslot, c2_b2, c2_a2, flg, zstrip, f2b, 64, 64, 32, 2);
    b2bpack<<<blocks(128 * 36 * 32), TB, 0, stream>>>(c2_kw, flg, wslot, 128 * 36 * 32);
    caun_v5<8><<<dim3(64, 2, 16), TB, 0, stream>>>(
        f2b, x2_1, 0, wslot, c2_kb, flg, x2up, 128, 32, 64, 64);

    // ---- block12: cat(x1_0 -> cl [64], x2up cl[128]) -> 64 -> 64 @128x128
    nchw2cl<<<2 * 2 * 256, TB, 0, stream>>>(x1_0, flg, x1cl, 64, 16384);
    wpk(b12_w1, wslot, 64, 192);
    conv3x3_lds<2, 1><<<cgN(128, 128, 64, 2), TB, 0, stream>>>(
        x1cl, 64, x2up, 128, wslot, b12_b1, nullptr, flg, zstrip, t1a, 128, 128, 64, 1);
    wpk(b12_w2, wslot, 64, 64);
    conv3x3_lds<2, 1><<<cgN(128, 128, 64, 2), TB, 0, stream>>>(
        nullptr, 0, t1a, 64, wslot, b12_b2, nullptr, flg, zstrip, x1_2, 128, 128, 64, 1);

    // ---- caun1: ctx = pool(x0_0) -> [2,128,128,32] cl
    pool2_cl<<<blocks(1048576), TB, 0, stream>>>(x0_0, flg, ctx1, 2, 32, 128, 128);
    wpk(c1_w1, wslot, 32, 32);
    conv3x3_lds<1, 0><<<cgN(128, 128, 32, 1), TB, 0, stream>>>(
        nullptr, 0, ctx1, 32, wslot, c1_b1, c1_a1, flg, zstrip, f1a, 128, 128, 32, 2);
    wpk(c1_w2, wslot, 16, 32);
    conv3x3_lds<1, 0><<<cgN(128, 128, 16, 1), TB, 0, stream>>>(
        nullptr, 0, f1a, 32, wslot, c1_b2, c1_a2, flg, zstrip, f1b, 128, 128, 16, 2);
    b2bpack<<<blocks(64 * 36 * 16), TB, 0, stream>>>(c1_kw, flg, kw1p, 64 * 36 * 16);
    caun_v5<8><<<dim3(256, 2, 8), TB, 0, stream>>>(
        f1b, x1_2, 0, kw1p, c1_kb, flg, x1up, 64, 16, 128, 128);

    // ---- block03: cat(x0_0 [32], x1up cl[64]) -> 32 -> 32 @256x256
    wpk(b03_w1, wtail, 32, 96);
    if (have_x0cl) {
        conv3x3_lds<2, 1><<<cgN(256, 256, 32, 2), TB, 0, stream>>>(
            x0cl, 32, x1up, 64, wtail, b03_b1, nullptr, flg, zstrip, t0a, 256, 256, 32, 1);
    } else {
        conv3x3_ext<4><<<dim3(16, 16, 4), TB, 0, stream>>>(
            x0_0, 32, x1up, 64, wtail, b03_b1, nullptr, flg, t0a, 256, 256, 32, 1);
    }
    wpk(b03_w2, wtail, 32, 32);
    conv3x3_lds<2, 1><<<cgN(256, 256, 32, 2), TB, 0, stream>>>(
        nullptr, 0, t0a, 32, wtail, b03_b2, nullptr, flg, zstrip, x0_3, 256, 256, 32, 1);

    // ---- fused memory-bank residual + final 1x1 conv -> [2,2,256,256]
    memfuse_final<<<512, TB, 0, stream>>>(x0_3, memw, fin_w, fin_b, flg, d_out, 256 * 256);
}

// Round 16
// 422.129 us; speedup vs baseline: 1.0673x; 1.0309x over previous
//
#include <hip/hip_runtime.h>
#include <hip/hip_bf16.h>
#include <math.h>

typedef __hip_bfloat16 bf16;
typedef short short8 __attribute__((ext_vector_type(8)));   // bf16x8 MFMA frag (4 VGPRs)
typedef float f32x4 __attribute__((ext_vector_type(4)));    // MFMA accumulator
typedef unsigned short us4 __attribute__((ext_vector_type(4)));

static __device__ __forceinline__ float b2f(bf16 x) { return __bfloat162float(x); }
static __device__ __forceinline__ bf16  f2b(float x) { return __float2bfloat16(x); }
static __device__ __forceinline__ short f2bs(float x) { bf16 t = f2b(x); return *reinterpret_cast<short*>(&t); }
static __device__ __forceinline__ float ex2(float x) { float r; asm("v_exp_f32 %0, %1" : "=v"(r) : "v"(x)); return r; }

// Polymorphic input load: isb=true -> bf16 storage, else f32 storage.
static __device__ __forceinline__ float ldin(const void* p, size_t i, bool isb) {
    return isb ? b2f(((const bf16*)p)[i]) : ((const float*)p)[i];
}

// ---------------------------------------------------------------- dtype detect (+ zero strip fill)
__global__ void detect_kernel(const unsigned int* __restrict__ x, float* __restrict__ flagp,
                              unsigned int* __restrict__ zstrip) {
    __shared__ int sh[64];
    for (int i = threadIdx.x; i < 256; i += 64) zstrip[i] = 0u;
    int insane = 0;
    for (int i = threadIdx.x; i < 1024; i += 64) {
        unsigned int lo = (x[i] & 0xFFFFu) << 16;
        float v = __uint_as_float(lo);
        if (!(fabsf(v) <= 1e6f)) insane++;
    }
    sh[threadIdx.x] = insane;
    __syncthreads();
    if (threadIdx.x == 0) {
        int t = 0;
        for (int i = 0; i < 64; ++i) t += sh[i];
        *flagp = (t < 16) ? 1.f : 0.f;            // 1 => inputs are bf16
    }
}

// ---------------------------------------------------------------- diagnostic fill
__global__ void diag_fill(unsigned int* __restrict__ out, int nwords, float val) {
    int i = blockIdx.x * blockDim.x + threadIdx.x;
    if (i < nwords) {
        unsigned short h = (unsigned short)(__float_as_uint(val) >> 16);
        out[i] = ((unsigned int)h << 16) | h;
    }
}

// ---------------------------------------------------------------- fused pack: up to 3 jobs per launch
// Round-28 post-mortem of r14/r15 failures: t0a is 4,194,304 elems
// (8388608..12582912) -- ANY pre-conv1 slot for b03_w2 either collides with
// t0a (output of conv1) or x1up (input of conv1). Fix: b03 packs revert to
// the proven round-13 two-launch ordering (w1 -> conv1 -> w2, both in wtail).
// All other pack slots audited with computed sizes: disjoint.
__global__ void pack3(const float* __restrict__ flg,
                      const void* __restrict__ s0, bf16* __restrict__ d0, int co0, int ci0,
                      const void* __restrict__ s1, bf16* __restrict__ d1, int co1, int ci1,
                      const void* __restrict__ s2, bf16* __restrict__ d2, int co2, int ci2,
                      int nb0, int nb01) {
    bool isb = (*flg != 0.f);
    int blk = blockIdx.x;
    const void* s; bf16* d; int co, ci;
    if (blk < nb0)        { s = s0; d = d0; co = co0; ci = ci0; }
    else if (blk < nb01)  { blk -= nb0;  s = s1; d = d1; co = co1; ci = ci1; }
    else                  { blk -= nb01; s = s2; d = d2; co = co2; ci = ci2; }
    int idx = blk * 256 + threadIdx.x;
    if (ci > 0) {
        int n = co * ci * 9;
        if (idx < n) {
            int c = idx % ci;
            int o = (idx / ci) % co;
            int tap = idx / (ci * co);
            d[idx] = f2b(ldin(s, ((size_t)o * ci + c) * 9 + tap, isb));
        }
    } else {
        if (idx < co) d[idx] = f2b(ldin(s, idx, isb));
    }
}

// ---------------------------------------------------------------- NCHW ext -> channels-last bf16 (LDS tile transpose)
__global__ void nchw2cl(const void* __restrict__ in, const float* __restrict__ flg,
                        bf16* __restrict__ out, int C, int HW) {
    __shared__ bf16 t[32][72];
    bool isb = (*flg != 0.f);
    int npx = HW >> 6, nc = C >> 5;
    int blk = blockIdx.x;
    int px0 = (blk % npx) << 6;
    int c0  = ((blk / npx) % nc) << 5;
    int b   = blk / (npx * nc);
    if (isb) {
        const bf16* pin = (const bf16*)in;
        for (int i = threadIdx.x; i < 512; i += 256) {
            int px4 = (i & 15) << 2, c = i >> 4;
            *(us4*)&t[c][px4] =
                *(const us4*)(pin + ((size_t)(b * C + c0 + c)) * HW + px0 + px4);
        }
    } else {
        const float* pf = (const float*)in;
        for (int i = threadIdx.x; i < 512; i += 256) {
            int px4 = (i & 15) << 2, c = i >> 4;
            float4 v = *(const float4*)(pf + ((size_t)(b * C + c0 + c)) * HW + px0 + px4);
            t[c][px4 + 0] = f2b(v.x);
            t[c][px4 + 1] = f2b(v.y);
            t[c][px4 + 2] = f2b(v.z);
            t[c][px4 + 3] = f2b(v.w);
        }
    }
    __syncthreads();
    for (int i = threadIdx.x; i < 512; i += 256) {
        int px = i >> 3, c4 = (i & 7) << 2;
        us4 v;
        v[0] = *(const unsigned short*)&t[c4 + 0][px];
        v[1] = *(const unsigned short*)&t[c4 + 1][px];
        v[2] = *(const unsigned short*)&t[c4 + 2][px];
        v[3] = *(const unsigned short*)&t[c4 + 3][px];
        *(us4*)&out[((size_t)b * HW + px0 + px) * C + c0 + c4] = v;
    }
}

// ---------------------------------------------------------------- 2x2 mean pool: NCHW ext -> channels-last bf16 ws
__global__ void pool2_cl(const void* __restrict__ in, const float* __restrict__ flg,
                         bf16* __restrict__ out, int B, int C, int H2, int W2) {
    bool isb = (*flg != 0.f);
    int idx = blockIdx.x * blockDim.x + threadIdx.x;
    int total = B * H2 * W2 * C;
    if (idx >= total) return;
    int c = idx % C;
    int pix = idx / C;
    int w = pix % W2;
    int h = (pix / W2) % H2;
    int b = pix / (W2 * H2);
    int H = H2 * 2, W = W2 * 2;
    size_t base = ((size_t)(b * C + c)) * H * W + (size_t)(2 * h) * W + 2 * w;
    float s;
    if (isb) {
        const bf16* pin = (const bf16*)in;
        unsigned int a = *(const unsigned int*)(pin + base);
        unsigned int d = *(const unsigned int*)(pin + base + W);
        float v00 = __uint_as_float(a << 16);
        float v01 = __uint_as_float(a & 0xFFFF0000u);
        float v10 = __uint_as_float(d << 16);
        float v11 = __uint_as_float(d & 0xFFFF0000u);
        s = v00 + v01 + v10 + v11;
    } else {
        const float* pf = (const float*)in;
        float2 r0 = *(const float2*)(pf + base);
        float2 r1 = *(const float2*)(pf + base + W);
        s = r0.x + r0.y + r1.x + r1.y;
    }
    out[idx] = f2b(0.25f * s);
}

// ---------------------------------------------------------------- MFMA conv3x3, LDS-staged, double-buffered
// Proven round-13 winner: RT=1 small convs, RT=2+WS1 big convs. WS1 = single-
// buffered w_s (10.4KB) with 2-barrier chunk schedule -> 36.3KB LDS at RT=2.
template<int RT, int WS1>
__global__ __launch_bounds__(256) void conv3x3_lds(
        const bf16* __restrict__ in1, int C1,
        const bf16* __restrict__ in2, int C2,
        const bf16* __restrict__ wp,
        const void* __restrict__ bias,
        const void* __restrict__ alpha,
        const float* __restrict__ flg,
        const char* __restrict__ zs,
        bf16* __restrict__ out,
        int H, int W, int Cout, int act) {
    constexpr int NRB = 4 * RT + 2;            // staged rows
    constexpr int NIU = NRB * 18 * 4;          // input 16B units
    constexpr int KI = (NIU + 255) / 256;
    constexpr int KW = 3;                      // 576 weight units / 256
    constexpr int NWB = WS1 ? 1 : 2;
    __shared__ bf16 in_s[2][NRB][18][36];      // [buf][row][px][ci pad 32->36]
    __shared__ bf16 w_s[NWB][9][16][36];       // [buf][tap][cout][ci pad]

    const bool isb = (*flg != 0.f);
    const int Cin = C1 + C2;
    const int tid = threadIdx.x;
    const int lane = tid & 63, wave = tid >> 6;
    const int quad = lane >> 4, l16 = lane & 15;
    const int cot = Cout >> 4;
    const int b = blockIdx.z / cot;
    const int co_base = (blockIdx.z % cot) << 4;
    const int r0b = blockIdx.y * (4 * RT);
    const int c0 = blockIdx.x << 4;
    const int cog = co_base + l16;

    // ---- chunk-invariant per-thread staging addresses
    const char* pin1[KI];
    const char* pin2[KI];
    #pragma unroll
    for (int k = 0; k < KI; ++k) {
        int u = min(tid + k * 256, NIU - 1);
        int sub = u & 3, px = (u >> 2) % 18, row = (u >> 2) / 18;
        int ih = r0b + row - 1, iw = c0 + px - 1;
        bool ok = (ih >= 0) && (ih < H) && (iw >= 0) && (iw < W);
        int ihc = min(max(ih, 0), H - 1), iwc = min(max(iw, 0), W - 1);
        size_t pix = (size_t)(b * H + ihc) * W + iwc;
        pin1[k] = (ok && C1 > 0) ? (const char*)(in1 + pix * C1 + sub * 8) : (zs + sub * 16);
        pin2[k] = ok ? (const char*)(in2 + pix * C2 + sub * 8) : (zs + sub * 16);
    }
    size_t offw[KW];
    #pragma unroll
    for (int k = 0; k < KW; ++k) {
        int u = min(tid + k * 256, 575);
        int sub = u & 3, cw = (u >> 2) & 15, tap = u >> 6;
        offw[k] = ((size_t)(tap * Cout + co_base + cw) * Cin + sub * 8) * 2;
    }
    const char* pw = (const char*)wp;

    short8 rin[KI], rwt[KW];
    auto issue = [&](int ci0) {
        const bool f1 = ci0 < C1;
        const int cl2 = (f1 ? ci0 : ci0 - C1) * 2;
        #pragma unroll
        for (int k = 0; k < KI; ++k)
            rin[k] = *(const short8*)((f1 ? pin1[k] : pin2[k]) + cl2);
        #pragma unroll
        for (int k = 0; k < KW; ++k)
            rwt[k] = *(const short8*)(pw + offw[k] + (size_t)ci0 * 2);
    };
    auto commit_in = [&](int bufi) {
        #pragma unroll
        for (int k = 0; k < KI; ++k) {
            int u = tid + k * 256;
            if (u < NIU) {
                int sub = u & 3, px = (u >> 2) % 18, row = (u >> 2) / 18;
                *(short8*)&in_s[bufi][row][px][sub * 8] = rin[k];
            }
        }
    };
    auto commit_w = [&](int bufi) {
        #pragma unroll
        for (int k = 0; k < KW; ++k) {
            int u = tid + k * 256;
            if (u < 576) {
                int sub = u & 3, cw = (u >> 2) & 15, tap = u >> 6;
                *(short8*)&w_s[bufi][tap][cw][sub * 8] = rwt[k];
            }
        }
    };

    float bv = ldin(bias, cog, isb);
    f32x4 acc[RT];
    #pragma unroll
    for (int t = 0; t < RT; ++t) acc[t] = {bv, bv, bv, bv};

    const int nchunk = Cin >> 5;
    issue(0);
    commit_in(0);
    commit_w(0);
    __syncthreads();
    int buf = 0;
    for (int ic = 0; ic < nchunk; ++ic) {
        const bool nx = (ic + 1 < nchunk);
        if (nx) issue((ic + 1) << 5);           // loads in flight over compute
        const int wbuf = WS1 ? 0 : buf;
        #pragma unroll
        for (int kw = 0; kw < 3; ++kw) {
            short8 F[RT + 2];
            #pragma unroll
            for (int j = 0; j < RT + 2; ++j)
                F[j] = *(const short8*)&in_s[buf][wave * RT + j][l16 + kw][quad * 8];
            #pragma unroll
            for (int kh = 0; kh < 3; ++kh) {
                short8 Wk = *(const short8*)&w_s[wbuf][kh * 3 + kw][l16][quad * 8];
                #pragma unroll
                for (int t = 0; t < RT; ++t)
                    acc[t] = __builtin_amdgcn_mfma_f32_16x16x32_bf16(F[t + kh], Wk, acc[t], 0, 0, 0);
            }
        }
        if (WS1) {
            if (nx) commit_in(buf ^ 1);         // waits rin only; rwt stays in flight
            __syncthreads();                    // all waves done reading w_s[0]
            if (nx) commit_w(0);                // weights for ic+1
            __syncthreads();                    // visible
        } else {
            if (nx) { commit_in(buf ^ 1); commit_w(buf ^ 1); }
            __syncthreads();
        }
        buf ^= 1;
    }

    float a = (act == 2) ? ldin(alpha, cog, isb) : 0.f;
    const int r0 = r0b + wave * RT;
    #pragma unroll
    for (int t = 0; t < RT; ++t) {
        #pragma unroll
        for (int reg = 0; reg < 4; ++reg) {
            float v = acc[t][reg];
            if (act == 1) v = fmaxf(v, 0.f);
            else if (act == 2) v = (v >= 0.f) ? v : a * v;
            out[(((size_t)(b * H) + r0 + t) * W + c0 + (quad << 2) + reg) * Cout + cog] = f2b(v);
        }
    }
}

// ---------------------------------------------------------------- MFMA conv3x3, ext-NCHW fallback
template<int RT>
__global__ __launch_bounds__(256) void conv3x3_ext(
        const void* __restrict__ in1, int C1,
        const bf16* __restrict__ in2, int C2,
        const bf16* __restrict__ wp,
        const void* __restrict__ bias,
        const void* __restrict__ alpha,
        const float* __restrict__ flg,
        bf16* __restrict__ out,
        int H, int W, int Cout, int act) {
    const bool isb = (*flg != 0.f);
    const int Cin = C1 + C2;
    const int lane = threadIdx.x & 63;
    const int wave = threadIdx.x >> 6;
    const int quad = lane >> 4, l16 = lane & 15;
    const int cot = Cout >> 4;
    const int b = blockIdx.z / cot;
    const int co_base = (blockIdx.z % cot) << 4;
    const int r0 = (blockIdx.y * 4 + wave) * RT;
    const int c0 = blockIdx.x << 4;
    const int cog = co_base + l16;

    float bv = ldin(bias, cog, isb);
    f32x4 acc[RT];
    #pragma unroll
    for (int t = 0; t < RT; ++t) acc[t] = {bv, bv, bv, bv};

    for (int ci0 = 0; ci0 < Cin; ci0 += 32) {
        const bool from1 = (ci0 < C1);
        #pragma unroll
        for (int kw = 0; kw < 3; ++kw) {
            const int iw = c0 + l16 + kw - 1;
            const bool okc = (iw >= 0) && (iw < W);
            short8 F[RT + 2];
            #pragma unroll
            for (int j = 0; j < RT + 2; ++j) {
                const int ih = r0 + j - 1;
                const bool ok = okc && (ih >= 0) && (ih < H);
                F[j] = short8{0, 0, 0, 0, 0, 0, 0, 0};
                if (from1) {
                    if (ok) {
                        size_t base = ((size_t)(b * C1 + ci0 + quad * 8)) * H * W
                                    + (size_t)ih * W + iw;
                        #pragma unroll
                        for (int jj = 0; jj < 8; ++jj)
                            F[j][jj] = f2bs(ldin(in1, base + (size_t)jj * H * W, isb));
                    }
                } else {
                    if (ok)
                        F[j] = *(const short8*)&in2[(((size_t)(b * H) + ih) * W + iw) * C2
                                                     + (ci0 - C1) + quad * 8];
                }
            }
            #pragma unroll
            for (int kh = 0; kh < 3; ++kh) {
                short8 bfrag = *(const short8*)&wp[((size_t)(kh * 3 + kw) * Cout + cog) * Cin
                                                   + ci0 + quad * 8];
                #pragma unroll
                for (int t = 0; t < RT; ++t)
                    acc[t] = __builtin_amdgcn_mfma_f32_16x16x32_bf16(F[t + kh], bfrag, acc[t], 0, 0, 0);
            }
        }
    }

    float a = (act == 2) ? ldin(alpha, cog, isb) : 0.f;
    #pragma unroll
    for (int t = 0; t < RT; ++t) {
        #pragma unroll
        for (int reg = 0; reg < 4; ++reg) {
            float v = acc[t][reg];
            if (act == 1) v = fmaxf(v, 0.f);
            else if (act == 2) v = (v >= 0.f) ? v : a * v;
            out[(((size_t)(b * H) + r0 + t) * W + c0 + (quad << 2) + reg) * Cout + cog] = f2b(v);
        }
    }
}

// ---------------------------------------------------------------- CAUN v5 (CC=8): unchanged (anchor)
template<int CC>
__global__ __launch_bounds__(256) void caun_v5(
        const bf16* __restrict__ f,
        const void* __restrict__ xlow, int xext,
        const bf16* __restrict__ kwp,
        const void* __restrict__ kb,
        const float* __restrict__ flg,
        bf16* __restrict__ out,
        int C, int K, int H, int W) {
    __shared__ float kb_s[CC * 40];             // [c][36 pad 40]
    __shared__ bf16  neigh_s[100 * (CC + 2)];   // [cell][c pad]
    __shared__ bf16  out_s[256 * (CC + 2)];     // [slot][c pad]

    const bool isb = (*flg != 0.f);
    const int tw = W >> 3;
    const int h0 = (blockIdx.x / tw) << 3;
    const int w0 = (blockIdx.x % tw) << 3;
    const int b  = blockIdx.y;
    const int c0 = blockIdx.z * CC;
    const int tid = threadIdx.x, wave = tid >> 6, lane = tid & 63;
    const int quad = lane >> 4, l16 = lane & 15;

    // ---- stage clamped neighbor halo (c-contiguous loads)
    for (int i = tid; i < 100 * CC; i += 256) {
        int c = i % CC, cell = i / CC;
        int r = cell / 10, q = cell % 10;
        int ih = min(max(h0 + r - 1, 0), H - 1);
        int iw = min(max(w0 + q - 1, 0), W - 1);
        float v = xext
            ? ldin(xlow, ((size_t)(b * C + c0 + c)) * H * W + (size_t)ih * W + iw, isb)
            : b2f(((const bf16*)xlow)[(((size_t)(b * H) + ih) * W + iw) * C + c0 + c]);
        neigh_s[cell * (CC + 2) + c] = f2b(v);
    }
    // ---- stage bias chunk, [c][j] layout (j-contiguous global reads)
    for (int i = tid; i < 36 * CC; i += 256) {
        int j = i % 36, c = i / 36;
        kb_s[c * 40 + j] = ldin(kb, (size_t)(c0 + c) * 36 + j, isb);
    }

    // ---- hoist B-frags (f) for this wave's 16 px (2 input rows x 8 cols)
    const int hl = (wave << 1) + (l16 >> 3);
    const int wl = l16 & 7;
    const size_t fpx = ((size_t)b * H * W + (size_t)(h0 + hl) * W + (w0 + wl)) * K;
    const int nkc = ((K + 31) & ~31) >> 5;          // 1 or 2
    const short8 z8 = {0, 0, 0, 0, 0, 0, 0, 0};
    short8 Bf[2];
    {
        int kq0 = quad * 8;
        Bf[0] = (kq0 < K) ? *(const short8*)&f[fpx + kq0] : z8;
        Bf[1] = (nkc > 1) ? *(const short8*)&f[fpx + 32 + quad * 8] : z8;
    }
    __syncthreads();

    // ---- per-lane tap cells: n = quad, 4+quad, 8 (for all 4 g-regs)
    const int nA = quad, nB = 4 + quad;
    const bf16* nbA = neigh_s + ((hl + nA / 3) * 10 + wl + nA % 3) * (CC + 2);
    const bf16* nbB = neigh_s + ((hl + nB / 3) * 10 + wl + nB % 3) * (CC + 2);
    const bf16* nbC = neigh_s + ((hl + 2) * 10 + wl + 2) * (CC + 2);
    const int x32 = ((lane ^ 32) & 63) << 2;        // bpermute byte index
    const bool q0 = (quad == 0);
    const bool bhi = (quad >> 1) != 0;              // q bit1 (lane bit5)
    const bool blo = (quad & 1) != 0;               // q bit0 (lane bit4)
    const bool l4 = (l16 < 4);
    bf16* osl = out_s + ((wave << 6) + lane) * (CC + 2);

    const char* pk = (const char*)kwp + (((size_t)c0 * 36 + l16) * K + quad * 8) * 2;
    const int dkc = 36 * K * 2;
    const int d16 = 16 * K * 2;
    const int d32 = 32 * K * 2;

    #pragma unroll 2
    for (int c = 0; c < CC; ++c) {
        const float* kbc = kb_s + c * 40;
        f32x4 a0 = *(const f32x4*)(kbc + (quad << 2));       // j = 4q+r
        f32x4 a1 = *(const f32x4*)(kbc + 16 + (quad << 2));  // j = 16+4q+r
        f32x4 a2 = *(const f32x4*)(kbc + 32);                // j = 32+r (q0 only)
        #pragma unroll
        for (int ch = 0; ch < 2; ++ch) {
            if (ch >= nkc) break;
            bool kok = (ch * 32 + quad * 8) < K;
            short8 f0 = kok ? *(const short8*)(pk + ch * 64) : z8;
            short8 f1 = kok ? *(const short8*)(pk + d16 + ch * 64) : z8;
            short8 f2 = (kok && l4) ? *(const short8*)(pk + d32 + ch * 64) : z8;
            a0 = __builtin_amdgcn_mfma_f32_16x16x32_bf16(f0, Bf[ch], a0, 0, 0, 0);
            a1 = __builtin_amdgcn_mfma_f32_16x16x32_bf16(f1, Bf[ch], a1, 0, 0, 0);
            a2 = __builtin_amdgcn_mfma_f32_16x16x32_bf16(f2, Bf[ch], a2, 0, 0, 0);
        }
        pk += dkc;
        float nv0 = b2f(nbA[c]), nv1 = b2f(nbB[c]), nv8 = b2f(nbC[c]);
        float Vs[4], Va[4];
        #pragma unroll
        for (int r = 0; r < 4; ++r) {
            float e0 = __expf(a0[r]);
            float e1 = __expf(a1[r]);
            float e2 = __expf(a2[r]);
            float e2m = q0 ? e2 : 0.f;
            Vs[r] = e0 + e1 + e2m;
            Va[r] = fmaf(e0, nv0, fmaf(e1, nv1, e2m * nv8));
        }
        // transpose-reduce over quads; lane ends with row r = quad.
        float sd0 = bhi ? Vs[0] : Vs[2];
        float sd1 = bhi ? Vs[1] : Vs[3];
        float sa0 = bhi ? Va[0] : Va[2];
        float sa1 = bhi ? Va[1] : Va[3];
        float rs0 = __int_as_float(__builtin_amdgcn_ds_bpermute(x32, __float_as_int(sd0)));
        float rs1 = __int_as_float(__builtin_amdgcn_ds_bpermute(x32, __float_as_int(sd1)));
        float ra0 = __int_as_float(__builtin_amdgcn_ds_bpermute(x32, __float_as_int(sa0)));
        float ra1 = __int_as_float(__builtin_amdgcn_ds_bpermute(x32, __float_as_int(sa1)));
        float Ps0 = (bhi ? Vs[2] : Vs[0]) + rs0;
        float Ps1 = (bhi ? Vs[3] : Vs[1]) + rs1;
        float Pa0 = (bhi ? Va[2] : Va[0]) + ra0;
        float Pa1 = (bhi ? Va[3] : Va[1]) + ra1;
        float ss = blo ? Ps0 : Ps1;
        float sa = blo ? Pa0 : Pa1;
        float qs = __int_as_float(__builtin_amdgcn_ds_swizzle(__float_as_int(ss), 0x401F));
        float qa = __int_as_float(__builtin_amdgcn_ds_swizzle(__float_as_int(sa), 0x401F));
        float Ss = (blo ? Ps1 : Ps0) + qs;
        float Sa = (blo ? Pa1 : Pa0) + qa;
        osl[c] = f2b(__fdividef(Sa, Ss));
    }

    __syncthreads();
    // ---- coalesced write-out: slot s = (wave, quad, hb, wl) -> (row, col)
    const size_t obase = (size_t)b * 4 * H * W;
    for (int i = tid; i < 256 * CC; i += 256) {
        int c = i % CC, s = i / CC;
        int wv = s >> 6, q = (s >> 4) & 3, hb = (s >> 3) & 1, wls = s & 7;
        int row_l = (wls << 1) + (q & 1);               // 2w + v
        int col_l = (((wv << 1) + hb) << 1) + (q >> 1); // 2h + u
        size_t P = obase + (size_t)(2 * w0 + row_l) * (2 * W) + (2 * h0 + col_l);
        out[P * C + c0 + c] = out_s[s * (CC + 2) + c];
    }
}

// ---------------------------------------------------------------- fused memory-bank + final 1x1 conv
__global__ __launch_bounds__(256, 2) void memfuse_final(
        const bf16* __restrict__ x, const void* __restrict__ memw,
        const void* __restrict__ fw, const void* __restrict__ fb,
        const float* __restrict__ flg, void* __restrict__ out, int HW) {
    __shared__ float mns[64 * 32];
    __shared__ float fws[66];
    const bool isb = (*flg != 0.f);
    if (threadIdx.x < 64) {
        int s = threadIdx.x;
        float v[32];
        float ss = 0.f;
        #pragma unroll
        for (int c = 0; c < 32; ++c) { v[c] = ldin(memw, s * 32 + c, isb); ss += v[c] * v[c]; }
        float inv = 1.f / fmaxf(sqrtf(ss), 1e-12f);
        #pragma unroll
        for (int c = 0; c < 32; ++c) mns[s * 32 + c] = v[c] * inv;
    } else if (threadIdx.x < 128) {
        int t = threadIdx.x - 64;
        fws[t] = ldin(fw, t, isb);
    } else if (threadIdx.x == 128) {
        fws[64] = ldin(fb, 0, isb);
        fws[65] = ldin(fb, 1, isb);
    }
    __syncthreads();

    int idx = blockIdx.x * blockDim.x + threadIdx.x;
    const bf16* xp = x + (size_t)idx * 32;

    float feat[32];
    float ss = 0.f;
    #pragma unroll
    for (int c = 0; c < 32; ++c) { feat[c] = b2f(xp[c]); ss += feat[c] * feat[c]; }
    float inv2 = 1.4426950408889634f / fmaxf(sqrtf(ss), 1e-12f);

    float se = 0.f;
    float racc[32];
    #pragma unroll
    for (int c = 0; c < 32; ++c) racc[c] = 0.f;

    for (int s = 0; s < 64; ++s) {
        const float* mr = mns + s * 32;
        float dot = 0.f;
        #pragma unroll
        for (int c = 0; c < 32; ++c) dot = fmaf(feat[c], mr[c], dot);
        float e = ex2(dot * inv2);
        se += e;
        #pragma unroll
        for (int c = 0; c < 32; ++c) racc[c] = fmaf(e, mr[c], racc[c]);
    }
    float rse = 1.f / se;
    float a0 = fws[64], a1 = fws[65];
    #pragma unroll
    for (int c = 0; c < 32; ++c) {
        float y = feat[c] + racc[c] * rse;
        a0 = fmaf(y, fws[c], a0);
        a1 = fmaf(y, fws[32 + c], a1);
    }
    int b = idx / HW, p = idx % HW;
    size_t i0 = (size_t)b * 2 * HW + p;
    size_t i1 = i0 + HW;
    if (isb) { ((bf16*)out)[i0] = f2b(a0); ((bf16*)out)[i1] = f2b(a1); }
    else     { ((float*)out)[i0] = a0;     ((float*)out)[i1] = a1; }
}

// ================================================================ host
extern "C" void kernel_launch(void* const* d_in, const int* in_sizes, int n_in,
                              void* d_out, int out_size, void* d_ws, size_t ws_size,
                              hipStream_t stream) {
    const void* x0_0 = d_in[0];
    const void* x1_0 = d_in[1];
    const void* x2_0 = d_in[2];
    const void* x3_0 = d_in[3];
    const void* c3_w1 = d_in[4];  const void* c3_b1 = d_in[5];  const void* c3_a1 = d_in[6];
    const void* c3_w2 = d_in[7];  const void* c3_b2 = d_in[8];  const void* c3_a2 = d_in[9];
    const void* c3_kw = d_in[10]; const void* c3_kb = d_in[11];
    const void* c2_w1 = d_in[12]; const void* c2_b1 = d_in[13]; const void* c2_a1 = d_in[14];
    const void* c2_w2 = d_in[15]; const void* c2_b2 = d_in[16]; const void* c2_a2 = d_in[17];
    const void* c2_kw = d_in[18]; const void* c2_kb = d_in[19];
    const void* c1_w1 = d_in[20]; const void* c1_b1 = d_in[21]; const void* c1_a1 = d_in[22];
    const void* c1_w2 = d_in[23]; const void* c1_b2 = d_in[24]; const void* c1_a2 = d_in[25];
    const void* c1_kw = d_in[26]; const void* c1_kb = d_in[27];
    const void* b21_w1 = d_in[28]; const void* b21_b1 = d_in[29];
    const void* b21_w2 = d_in[30]; const void* b21_b2 = d_in[31];
    const void* b12_w1 = d_in[32]; const void* b12_b1 = d_in[33];
    const void* b12_w2 = d_in[34]; const void* b12_b2 = d_in[35];
    const void* b03_w1 = d_in[36]; const void* b03_b1 = d_in[37];
    const void* b03_w2 = d_in[38]; const void* b03_b2 = d_in[39];
    const void* fin_w = d_in[40];  const void* fin_b = d_in[41];
    const void* memw  = d_in[42];
    (void)in_sizes; (void)n_in;

    const int TB = 256;
    auto blocks = [](int n) { return (n + 255) / 256; };

    const size_t NEED = 25165824 + 65536;
    if (ws_size < NEED) {
        diag_fill<<<blocks(out_size / 2), TB, 0, stream>>>(
            (unsigned int*)d_out, out_size / 2, (float)ws_size);
        return;
    }
    const size_t NEED_X0 = 25165824 + 8388608 + 65536 + 256;
    const bool have_x0cl = (ws_size >= NEED_X0);

    size_t tail = (ws_size - 65536) & ~(size_t)255;
    bf16*  wtail = (bf16*)((char*)d_ws + tail);
    float* flg   = (float*)((char*)d_ws + tail + 63488);
    char*  zstrip = (char*)d_ws + tail + 63744;     // 1 KiB zero strip

    // 24 MiB arena (12,582,912 bf16 elems), channels-last, verified live ranges.
    bf16* A = (bf16*)d_ws;
    bf16* x3up  = A + 0;         // [2,64,64,256] (0..2097152)
    bf16* ctx3p = A + 2097152;   // [2,32,32,128]
    bf16* f3a   = A + 2359296;   // [2,32,32,128]
    bf16* f3b   = A + 2621440;   // [2,32,32,64]
    bf16* kw3p  = A + 3000000;   // 589,824 elems (3000000..3589824)
    bf16* t2a   = A + 2097152;   // [2,64,64,128] (2097152..3145728)
    bf16* x2cl  = A + 3145728;   // [2,64,64,128] (3145728..4194304)
    bf16* x2_1  = A + 0;         // [2,64,64,128] (0..1048576)
    bf16* ctx2  = A + 1048576;   // [2,64,64,64]
    bf16* f2a   = A + 1572864;   // [2,64,64,64]
    bf16* f2b_  = A + 2097152;   // [2,64,64,32]
    bf16* x2up  = A + 2359296;   // [2,128,128,128] (ends 6553600)
    bf16* t1a   = A + 0;         // [2,128,128,64] (0..2097152)
    bf16* x1cl  = A + 6995968;   // [2,128,128,64] (6995968..9093120)
    bf16* x1_2  = A + 10485760;  // [2,128,128,64] (10485760..12582912)
    bf16* ctx1  = A + 4194304;   // [2,128,128,32]
    bf16* f1a   = A + 5242880;   // [2,128,128,32]
    bf16* f1b   = A + 9437184;   // [2,128,128,16] (9437184..9961472)
    bf16* kw1p  = A + 8388608;   // caun1 kw: past x1up end (x1up = 0..8388608)
    bf16* x1up  = A + 0;         // [2,256,256,64] (0..8388608)
    bf16* t0a   = A + 8388608;   // [2,256,256,32] (8388608..12582912!)
    bf16* x0_3  = A + 0;         // [2,256,256,32] (0..4194304)
    bf16* wslot = A + 6553600;   // weight slot (6553600..6995968, above x2up end)
    bf16* bw2   = A + 4194304;   // b21_w2 slot (free during b21 stage)
    bf16* x0cl  = A + 12582912;  // [2,256,256,32] (only if have_x0cl)

    detect_kernel<<<1, 64, 0, stream>>>((const unsigned int*)x0_0, flg, (unsigned int*)zstrip);

    // fused pack launcher: up to 3 jobs (ci>0 wpack; ci==0 flat copy of co elems)
    auto pk3 = [&](const void* s0, bf16* d0, int co0, int ci0,
                   const void* s1, bf16* d1, int co1, int ci1,
                   const void* s2, bf16* d2, int co2, int ci2) {
        int n0 = ci0 ? co0 * ci0 * 9 : co0;
        int n1 = s1 ? (ci1 ? co1 * ci1 * 9 : co1) : 0;
        int n2 = s2 ? (ci2 ? co2 * ci2 * 9 : co2) : 0;
        int b0 = (n0 + 255) / 256, b1 = (n1 + 255) / 256, b2c = (n2 + 255) / 256;
        pack3<<<b0 + b1 + b2c, TB, 0, stream>>>(flg,
            s0, d0, co0, ci0, s1, d1, co1, ci1, s2, d2, co2, ci2, b0, b0 + b1);
    };
    auto cgN = [](int H, int W, int Cout, int RT) {
        return dim3(W >> 4, H / (4 * RT), 2 * (Cout >> 4));
    };

    if (have_x0cl)
        nchw2cl<<<2 * 1 * 1024, TB, 0, stream>>>(x0_0, flg, x0cl, 32, 65536);

    // ---- caun3: ctx = pool(x2_0) -> [2,32,32,128] cl
    pool2_cl<<<blocks(262144), TB, 0, stream>>>(x2_0, flg, ctx3p, 2, 128, 32, 32);
    pk3(c3_w1, wslot, 128, 128,
        c3_w2, wslot + 147456, 64, 128,
        c3_kw, kw3p, 256 * 36 * 64, 0);
    conv3x3_lds<1, 0><<<cgN(32, 32, 128, 1), TB, 0, stream>>>(
        nullptr, 0, ctx3p, 128, wslot, c3_b1, c3_a1, flg, zstrip, f3a, 32, 32, 128, 2);
    conv3x3_lds<1, 0><<<cgN(32, 32, 64, 1), TB, 0, stream>>>(
        nullptr, 0, f3a, 128, wslot + 147456, c3_b2, c3_a2, flg, zstrip, f3b, 32, 32, 64, 2);
    caun_v5<8><<<dim3(16, 2, 32), TB, 0, stream>>>(
        f3b, x3_0, 1, kw3p, c3_kb, flg, x3up, 256, 64, 32, 32);

    // ---- block21: cat(x2_0 -> cl [128], x3up cl[256]) -> 128 -> 128 @64x64
    nchw2cl<<<2 * 4 * 64, TB, 0, stream>>>(x2_0, flg, x2cl, 128, 4096);
    pk3(b21_w1, wslot, 128, 384,
        b21_w2, bw2, 128, 128,
        nullptr, nullptr, 0, 0);
    conv3x3_lds<1, 0><<<cgN(64, 64, 128, 1), TB, 0, stream>>>(
        x2cl, 128, x3up, 256, wslot, b21_b1, nullptr, flg, zstrip, t2a, 64, 64, 128, 1);
    conv3x3_lds<1, 0><<<cgN(64, 64, 128, 1), TB, 0, stream>>>(
        nullptr, 0, t2a, 128, bw2, b21_b2, nullptr, flg, zstrip, x2_1, 64, 64, 128, 1);

    // ---- caun2: ctx = pool(x1_0) -> [2,64,64,64] cl
    pool2_cl<<<blocks(524288), TB, 0, stream>>>(x1_0, flg, ctx2, 2, 64, 64, 64);
    pk3(c2_w1, wslot, 64, 64,
        c2_w2, wslot + 36864, 32, 64,
        c2_kw, wslot + 55296, 128 * 36 * 32, 0);
    conv3x3_lds<1, 0><<<cgN(64, 64, 64, 1), TB, 0, stream>>>(
        nullptr, 0, ctx2, 64, wslot, c2_b1, c2_a1, flg, zstrip, f2a, 64, 64, 64, 2);
    conv3x3_lds<1, 0><<<cgN(64, 64, 32, 1), TB, 0, stream>>>(
        nullptr, 0, f2a, 64, wslot + 36864, c2_b2, c2_a2, flg, zstrip, f2b_, 64, 64, 32, 2);
    caun_v5<8><<<dim3(64, 2, 16), TB, 0, stream>>>(
        f2b_, x2_1, 0, wslot + 55296, c2_kb, flg, x2up, 128, 32, 64, 64);

    // ---- block12: cat(x1_0 -> cl [64], x2up cl[128]) -> 64 -> 64 @128x128
    nchw2cl<<<2 * 2 * 256, TB, 0, stream>>>(x1_0, flg, x1cl, 64, 16384);
    pk3(b12_w1, wslot, 64, 192,
        b12_w2, wslot + 110592, 64, 64,
        nullptr, nullptr, 0, 0);
    conv3x3_lds<2, 1><<<cgN(128, 128, 64, 2), TB, 0, stream>>>(
        x1cl, 64, x2up, 128, wslot, b12_b1, nullptr, flg, zstrip, t1a, 128, 128, 64, 1);
    conv3x3_lds<2, 1><<<cgN(128, 128, 64, 2), TB, 0, stream>>>(
        nullptr, 0, t1a, 64, wslot + 110592, b12_b2, nullptr, flg, zstrip, x1_2, 128, 128, 64, 1);

    // ---- caun1: ctx = pool(x0_0) -> [2,128,128,32] cl
    pool2_cl<<<blocks(1048576), TB, 0, stream>>>(x0_0, flg, ctx1, 2, 32, 128, 128);
    pk3(c1_w1, wslot, 32, 32,
        c1_w2, wslot + 9216, 16, 32,
        c1_kw, kw1p, 64 * 36 * 16, 0);
    conv3x3_lds<1, 0><<<cgN(128, 128, 32, 1), TB, 0, stream>>>(
        nullptr, 0, ctx1, 32, wslot, c1_b1, c1_a1, flg, zstrip, f1a, 128, 128, 32, 2);
    conv3x3_lds<1, 0><<<cgN(128, 128, 16, 1), TB, 0, stream>>>(
        nullptr, 0, f1a, 32, wslot + 9216, c1_b2, c1_a2, flg, zstrip, f1b, 128, 128, 16, 2);
    caun_v5<8><<<dim3(256, 2, 8), TB, 0, stream>>>(
        f1b, x1_2, 0, kw1p, c1_kb, flg, x1up, 64, 16, 128, 128);

    // ---- block03: cat(x0_0 [32], x1up cl[64]) -> 32 -> 32 @256x256
    // t0a spans 8388608..12582912 -> NO pre-conv1 slot for b03_w2 is safe
    // (below 8388608 is x1up = conv1 input). Proven round-13 two-step packs.
    pk3(b03_w1, wtail, 32, 96, nullptr, nullptr, 0, 0, nullptr, nullptr, 0, 0);
    if (have_x0cl) {
        conv3x3_lds<2, 1><<<cgN(256, 256, 32, 2), TB, 0, stream>>>(
            x0cl, 32, x1up, 64, wtail, b03_b1, nullptr, flg, zstrip, t0a, 256, 256, 32, 1);
    } else {
        conv3x3_ext<4><<<dim3(16, 16, 4), TB, 0, stream>>>(
            x0_0, 32, x1up, 64, wtail, b03_b1, nullptr, flg, t0a, 256, 256, 32, 1);
    }
    pk3(b03_w2, wtail, 32, 32, nullptr, nullptr, 0, 0, nullptr, nullptr, 0, 0);
    conv3x3_lds<2, 1><<<cgN(256, 256, 32, 2), TB, 0, stream>>>(
        nullptr, 0, t0a, 32, wtail, b03_b2, nullptr, flg, zstrip, x0_3, 256, 256, 32, 1);

    // ---- fused memory-bank residual + final 1x1 conv -> [2,2,256,256]
    memfuse_final<<<512, TB, 0, stream>>>(x0_3, memw, fin_w, fin_b, flg, d_out, 256 * 256);
}

// Round 17
// 419.859 us; speedup vs baseline: 1.0731x; 1.0054x over previous
//
#include <hip/hip_runtime.h>
#include <hip/hip_bf16.h>
#include <math.h>

typedef __hip_bfloat16 bf16;
typedef short short8 __attribute__((ext_vector_type(8)));   // bf16x8 MFMA frag (4 VGPRs)
typedef float f32x4 __attribute__((ext_vector_type(4)));    // MFMA accumulator
typedef unsigned short us4 __attribute__((ext_vector_type(4)));

static __device__ __forceinline__ float b2f(bf16 x) { return __bfloat162float(x); }
static __device__ __forceinline__ bf16  f2b(float x) { return __float2bfloat16(x); }
static __device__ __forceinline__ short f2bs(float x) { bf16 t = f2b(x); return *reinterpret_cast<short*>(&t); }
static __device__ __forceinline__ float ex2(float x) { float r; asm("v_exp_f32 %0, %1" : "=v"(r) : "v"(x)); return r; }

// Polymorphic input load: isb=true -> bf16 storage, else f32 storage.
static __device__ __forceinline__ float ldin(const void* p, size_t i, bool isb) {
    return isb ? b2f(((const bf16*)p)[i]) : ((const float*)p)[i];
}

// ---------------------------------------------------------------- dtype detect (+ zero strip fill)
__global__ void detect_kernel(const unsigned int* __restrict__ x, float* __restrict__ flagp,
                              unsigned int* __restrict__ zstrip) {
    __shared__ int sh[64];
    for (int i = threadIdx.x; i < 256; i += 64) zstrip[i] = 0u;
    int insane = 0;
    for (int i = threadIdx.x; i < 1024; i += 64) {
        unsigned int lo = (x[i] & 0xFFFFu) << 16;
        float v = __uint_as_float(lo);
        if (!(fabsf(v) <= 1e6f)) insane++;
    }
    sh[threadIdx.x] = insane;
    __syncthreads();
    if (threadIdx.x == 0) {
        int t = 0;
        for (int i = 0; i < 64; ++i) t += sh[i];
        *flagp = (t < 16) ? 1.f : 0.f;            // 1 => inputs are bf16
    }
}

// ---------------------------------------------------------------- diagnostic fill
__global__ void diag_fill(unsigned int* __restrict__ out, int nwords, float val) {
    int i = blockIdx.x * blockDim.x + threadIdx.x;
    if (i < nwords) {
        unsigned short h = (unsigned short)(__float_as_uint(val) >> 16);
        out[i] = ((unsigned int)h << 16) | h;
    }
}

// ---------------------------------------------------------------- fused pack: up to 3 jobs per launch
__global__ void pack3(const float* __restrict__ flg,
                      const void* __restrict__ s0, bf16* __restrict__ d0, int co0, int ci0,
                      const void* __restrict__ s1, bf16* __restrict__ d1, int co1, int ci1,
                      const void* __restrict__ s2, bf16* __restrict__ d2, int co2, int ci2,
                      int nb0, int nb01) {
    bool isb = (*flg != 0.f);
    int blk = blockIdx.x;
    const void* s; bf16* d; int co, ci;
    if (blk < nb0)        { s = s0; d = d0; co = co0; ci = ci0; }
    else if (blk < nb01)  { blk -= nb0;  s = s1; d = d1; co = co1; ci = ci1; }
    else                  { blk -= nb01; s = s2; d = d2; co = co2; ci = ci2; }
    int idx = blk * 256 + threadIdx.x;
    if (ci > 0) {
        int n = co * ci * 9;
        if (idx < n) {
            int c = idx % ci;
            int o = (idx / ci) % co;
            int tap = idx / (ci * co);
            d[idx] = f2b(ldin(s, ((size_t)o * ci + c) * 9 + tap, isb));
        }
    } else {
        if (idx < co) d[idx] = f2b(ldin(s, idx, isb));
    }
}

// ---------------------------------------------------------------- NCHW ext -> channels-last bf16 (LDS tile transpose)
__global__ void nchw2cl(const void* __restrict__ in, const float* __restrict__ flg,
                        bf16* __restrict__ out, int C, int HW) {
    __shared__ bf16 t[32][72];
    bool isb = (*flg != 0.f);
    int npx = HW >> 6, nc = C >> 5;
    int blk = blockIdx.x;
    int px0 = (blk % npx) << 6;
    int c0  = ((blk / npx) % nc) << 5;
    int b   = blk / (npx * nc);
    if (isb) {
        const bf16* pin = (const bf16*)in;
        for (int i = threadIdx.x; i < 512; i += 256) {
            int px4 = (i & 15) << 2, c = i >> 4;
            *(us4*)&t[c][px4] =
                *(const us4*)(pin + ((size_t)(b * C + c0 + c)) * HW + px0 + px4);
        }
    } else {
        const float* pf = (const float*)in;
        for (int i = threadIdx.x; i < 512; i += 256) {
            int px4 = (i & 15) << 2, c = i >> 4;
            float4 v = *(const float4*)(pf + ((size_t)(b * C + c0 + c)) * HW + px0 + px4);
            t[c][px4 + 0] = f2b(v.x);
            t[c][px4 + 1] = f2b(v.y);
            t[c][px4 + 2] = f2b(v.z);
            t[c][px4 + 3] = f2b(v.w);
        }
    }
    __syncthreads();
    for (int i = threadIdx.x; i < 512; i += 256) {
        int px = i >> 3, c4 = (i & 7) << 2;
        us4 v;
        v[0] = *(const unsigned short*)&t[c4 + 0][px];
        v[1] = *(const unsigned short*)&t[c4 + 1][px];
        v[2] = *(const unsigned short*)&t[c4 + 2][px];
        v[3] = *(const unsigned short*)&t[c4 + 3][px];
        *(us4*)&out[((size_t)b * HW + px0 + px) * C + c0 + c4] = v;
    }
}

// ---------------------------------------------------------------- 2x2 mean pool: NCHW ext -> channels-last bf16 ws
__global__ void pool2_cl(const void* __restrict__ in, const float* __restrict__ flg,
                         bf16* __restrict__ out, int B, int C, int H2, int W2) {
    bool isb = (*flg != 0.f);
    int idx = blockIdx.x * blockDim.x + threadIdx.x;
    int total = B * H2 * W2 * C;
    if (idx >= total) return;
    int c = idx % C;
    int pix = idx / C;
    int w = pix % W2;
    int h = (pix / W2) % H2;
    int b = pix / (W2 * H2);
    int H = H2 * 2, W = W2 * 2;
    size_t base = ((size_t)(b * C + c)) * H * W + (size_t)(2 * h) * W + 2 * w;
    float s;
    if (isb) {
        const bf16* pin = (const bf16*)in;
        unsigned int a = *(const unsigned int*)(pin + base);
        unsigned int d = *(const unsigned int*)(pin + base + W);
        float v00 = __uint_as_float(a << 16);
        float v01 = __uint_as_float(a & 0xFFFF0000u);
        float v10 = __uint_as_float(d << 16);
        float v11 = __uint_as_float(d & 0xFFFF0000u);
        s = v00 + v01 + v10 + v11;
    } else {
        const float* pf = (const float*)in;
        float2 r0 = *(const float2*)(pf + base);
        float2 r1 = *(const float2*)(pf + base + W);
        s = r0.x + r0.y + r1.x + r1.y;
    }
    out[idx] = f2b(0.25f * s);
}

// ---------------------------------------------------------------- MFMA conv3x3, LDS-staged, double-buffered
// Round-29: WS1 (single-buffered w_s, 2-barrier schedule) extended to ALL
// convs. Mechanism proven on big convs in r13: occupancy. Small RT=1 convs:
// LDS 35.4KB (4 blocks/CU) -> 25.3KB (6 blocks/CU, +50% waves). Numerics
// bitwise identical (MFMA order unchanged).
template<int RT, int WS1>
__global__ __launch_bounds__(256) void conv3x3_lds(
        const bf16* __restrict__ in1, int C1,
        const bf16* __restrict__ in2, int C2,
        const bf16* __restrict__ wp,
        const void* __restrict__ bias,
        const void* __restrict__ alpha,
        const float* __restrict__ flg,
        const char* __restrict__ zs,
        bf16* __restrict__ out,
        int H, int W, int Cout, int act) {
    constexpr int NRB = 4 * RT + 2;            // staged rows
    constexpr int NIU = NRB * 18 * 4;          // input 16B units
    constexpr int KI = (NIU + 255) / 256;
    constexpr int KW = 3;                      // 576 weight units / 256
    constexpr int NWB = WS1 ? 1 : 2;
    __shared__ bf16 in_s[2][NRB][18][36];      // [buf][row][px][ci pad 32->36]
    __shared__ bf16 w_s[NWB][9][16][36];       // [buf][tap][cout][ci pad]

    const bool isb = (*flg != 0.f);
    const int Cin = C1 + C2;
    const int tid = threadIdx.x;
    const int lane = tid & 63, wave = tid >> 6;
    const int quad = lane >> 4, l16 = lane & 15;
    const int cot = Cout >> 4;
    const int b = blockIdx.z / cot;
    const int co_base = (blockIdx.z % cot) << 4;
    const int r0b = blockIdx.y * (4 * RT);
    const int c0 = blockIdx.x << 4;
    const int cog = co_base + l16;

    // ---- chunk-invariant per-thread staging addresses
    const char* pin1[KI];
    const char* pin2[KI];
    #pragma unroll
    for (int k = 0; k < KI; ++k) {
        int u = min(tid + k * 256, NIU - 1);
        int sub = u & 3, px = (u >> 2) % 18, row = (u >> 2) / 18;
        int ih = r0b + row - 1, iw = c0 + px - 1;
        bool ok = (ih >= 0) && (ih < H) && (iw >= 0) && (iw < W);
        int ihc = min(max(ih, 0), H - 1), iwc = min(max(iw, 0), W - 1);
        size_t pix = (size_t)(b * H + ihc) * W + iwc;
        pin1[k] = (ok && C1 > 0) ? (const char*)(in1 + pix * C1 + sub * 8) : (zs + sub * 16);
        pin2[k] = ok ? (const char*)(in2 + pix * C2 + sub * 8) : (zs + sub * 16);
    }
    size_t offw[KW];
    #pragma unroll
    for (int k = 0; k < KW; ++k) {
        int u = min(tid + k * 256, 575);
        int sub = u & 3, cw = (u >> 2) & 15, tap = u >> 6;
        offw[k] = ((size_t)(tap * Cout + co_base + cw) * Cin + sub * 8) * 2;
    }
    const char* pw = (const char*)wp;

    short8 rin[KI], rwt[KW];
    auto issue = [&](int ci0) {
        const bool f1 = ci0 < C1;
        const int cl2 = (f1 ? ci0 : ci0 - C1) * 2;
        #pragma unroll
        for (int k = 0; k < KI; ++k)
            rin[k] = *(const short8*)((f1 ? pin1[k] : pin2[k]) + cl2);
        #pragma unroll
        for (int k = 0; k < KW; ++k)
            rwt[k] = *(const short8*)(pw + offw[k] + (size_t)ci0 * 2);
    };
    auto commit_in = [&](int bufi) {
        #pragma unroll
        for (int k = 0; k < KI; ++k) {
            int u = tid + k * 256;
            if (u < NIU) {
                int sub = u & 3, px = (u >> 2) % 18, row = (u >> 2) / 18;
                *(short8*)&in_s[bufi][row][px][sub * 8] = rin[k];
            }
        }
    };
    auto commit_w = [&](int bufi) {
        #pragma unroll
        for (int k = 0; k < KW; ++k) {
            int u = tid + k * 256;
            if (u < 576) {
                int sub = u & 3, cw = (u >> 2) & 15, tap = u >> 6;
                *(short8*)&w_s[bufi][tap][cw][sub * 8] = rwt[k];
            }
        }
    };

    float bv = ldin(bias, cog, isb);
    f32x4 acc[RT];
    #pragma unroll
    for (int t = 0; t < RT; ++t) acc[t] = {bv, bv, bv, bv};

    const int nchunk = Cin >> 5;
    issue(0);
    commit_in(0);
    commit_w(0);
    __syncthreads();
    int buf = 0;
    for (int ic = 0; ic < nchunk; ++ic) {
        const bool nx = (ic + 1 < nchunk);
        if (nx) issue((ic + 1) << 5);           // loads in flight over compute
        const int wbuf = WS1 ? 0 : buf;
        #pragma unroll
        for (int kw = 0; kw < 3; ++kw) {
            short8 F[RT + 2];
            #pragma unroll
            for (int j = 0; j < RT + 2; ++j)
                F[j] = *(const short8*)&in_s[buf][wave * RT + j][l16 + kw][quad * 8];
            #pragma unroll
            for (int kh = 0; kh < 3; ++kh) {
                short8 Wk = *(const short8*)&w_s[wbuf][kh * 3 + kw][l16][quad * 8];
                #pragma unroll
                for (int t = 0; t < RT; ++t)
                    acc[t] = __builtin_amdgcn_mfma_f32_16x16x32_bf16(F[t + kh], Wk, acc[t], 0, 0, 0);
            }
        }
        if (WS1) {
            if (nx) commit_in(buf ^ 1);         // waits rin only; rwt stays in flight
            __syncthreads();                    // all waves done reading w_s[0]
            if (nx) commit_w(0);                // weights for ic+1
            __syncthreads();                    // visible
        } else {
            if (nx) { commit_in(buf ^ 1); commit_w(buf ^ 1); }
            __syncthreads();
        }
        buf ^= 1;
    }

    float a = (act == 2) ? ldin(alpha, cog, isb) : 0.f;
    const int r0 = r0b + wave * RT;
    #pragma unroll
    for (int t = 0; t < RT; ++t) {
        #pragma unroll
        for (int reg = 0; reg < 4; ++reg) {
            float v = acc[t][reg];
            if (act == 1) v = fmaxf(v, 0.f);
            else if (act == 2) v = (v >= 0.f) ? v : a * v;
            out[(((size_t)(b * H) + r0 + t) * W + c0 + (quad << 2) + reg) * Cout + cog] = f2b(v);
        }
    }
}

// ---------------------------------------------------------------- MFMA conv3x3, ext-NCHW fallback
template<int RT>
__global__ __launch_bounds__(256) void conv3x3_ext(
        const void* __restrict__ in1, int C1,
        const bf16* __restrict__ in2, int C2,
        const bf16* __restrict__ wp,
        const void* __restrict__ bias,
        const void* __restrict__ alpha,
        const float* __restrict__ flg,
        bf16* __restrict__ out,
        int H, int W, int Cout, int act) {
    const bool isb = (*flg != 0.f);
    const int Cin = C1 + C2;
    const int lane = threadIdx.x & 63;
    const int wave = threadIdx.x >> 6;
    const int quad = lane >> 4, l16 = lane & 15;
    const int cot = Cout >> 4;
    const int b = blockIdx.z / cot;
    const int co_base = (blockIdx.z % cot) << 4;
    const int r0 = (blockIdx.y * 4 + wave) * RT;
    const int c0 = blockIdx.x << 4;
    const int cog = co_base + l16;

    float bv = ldin(bias, cog, isb);
    f32x4 acc[RT];
    #pragma unroll
    for (int t = 0; t < RT; ++t) acc[t] = {bv, bv, bv, bv};

    for (int ci0 = 0; ci0 < Cin; ci0 += 32) {
        const bool from1 = (ci0 < C1);
        #pragma unroll
        for (int kw = 0; kw < 3; ++kw) {
            const int iw = c0 + l16 + kw - 1;
            const bool okc = (iw >= 0) && (iw < W);
            short8 F[RT + 2];
            #pragma unroll
            for (int j = 0; j < RT + 2; ++j) {
                const int ih = r0 + j - 1;
                const bool ok = okc && (ih >= 0) && (ih < H);
                F[j] = short8{0, 0, 0, 0, 0, 0, 0, 0};
                if (from1) {
                    if (ok) {
                        size_t base = ((size_t)(b * C1 + ci0 + quad * 8)) * H * W
                                    + (size_t)ih * W + iw;
                        #pragma unroll
                        for (int jj = 0; jj < 8; ++jj)
                            F[j][jj] = f2bs(ldin(in1, base + (size_t)jj * H * W, isb));
                    }
                } else {
                    if (ok)
                        F[j] = *(const short8*)&in2[(((size_t)(b * H) + ih) * W + iw) * C2
                                                     + (ci0 - C1) + quad * 8];
                }
            }
            #pragma unroll
            for (int kh = 0; kh < 3; ++kh) {
                short8 bfrag = *(const short8*)&wp[((size_t)(kh * 3 + kw) * Cout + cog) * Cin
                                                   + ci0 + quad * 8];
                #pragma unroll
                for (int t = 0; t < RT; ++t)
                    acc[t] = __builtin_amdgcn_mfma_f32_16x16x32_bf16(F[t + kh], bfrag, acc[t], 0, 0, 0);
            }
        }
    }

    float a = (act == 2) ? ldin(alpha, cog, isb) : 0.f;
    #pragma unroll
    for (int t = 0; t < RT; ++t) {
        #pragma unroll
        for (int reg = 0; reg < 4; ++reg) {
            float v = acc[t][reg];
            if (act == 1) v = fmaxf(v, 0.f);
            else if (act == 2) v = (v >= 0.f) ? v : a * v;
            out[(((size_t)(b * H) + r0 + t) * W + c0 + (quad << 2) + reg) * Cout + cog] = f2b(v);
        }
    }
}

// ---------------------------------------------------------------- CAUN v5 (CC=8): unchanged (anchor)
template<int CC>
__global__ __launch_bounds__(256) void caun_v5(
        const bf16* __restrict__ f,
        const void* __restrict__ xlow, int xext,
        const bf16* __restrict__ kwp,
        const void* __restrict__ kb,
        const float* __restrict__ flg,
        bf16* __restrict__ out,
        int C, int K, int H, int W) {
    __shared__ float kb_s[CC * 40];             // [c][36 pad 40]
    __shared__ bf16  neigh_s[100 * (CC + 2)];   // [cell][c pad]
    __shared__ bf16  out_s[256 * (CC + 2)];     // [slot][c pad]

    const bool isb = (*flg != 0.f);
    const int tw = W >> 3;
    const int h0 = (blockIdx.x / tw) << 3;
    const int w0 = (blockIdx.x % tw) << 3;
    const int b  = blockIdx.y;
    const int c0 = blockIdx.z * CC;
    const int tid = threadIdx.x, wave = tid >> 6, lane = tid & 63;
    const int quad = lane >> 4, l16 = lane & 15;

    // ---- stage clamped neighbor halo (c-contiguous loads)
    for (int i = tid; i < 100 * CC; i += 256) {
        int c = i % CC, cell = i / CC;
        int r = cell / 10, q = cell % 10;
        int ih = min(max(h0 + r - 1, 0), H - 1);
        int iw = min(max(w0 + q - 1, 0), W - 1);
        float v = xext
            ? ldin(xlow, ((size_t)(b * C + c0 + c)) * H * W + (size_t)ih * W + iw, isb)
            : b2f(((const bf16*)xlow)[(((size_t)(b * H) + ih) * W + iw) * C + c0 + c]);
        neigh_s[cell * (CC + 2) + c] = f2b(v);
    }
    // ---- stage bias chunk, [c][j] layout (j-contiguous global reads)
    for (int i = tid; i < 36 * CC; i += 256) {
        int j = i % 36, c = i / 36;
        kb_s[c * 40 + j] = ldin(kb, (size_t)(c0 + c) * 36 + j, isb);
    }

    // ---- hoist B-frags (f) for this wave's 16 px (2 input rows x 8 cols)
    const int hl = (wave << 1) + (l16 >> 3);
    const int wl = l16 & 7;
    const size_t fpx = ((size_t)b * H * W + (size_t)(h0 + hl) * W + (w0 + wl)) * K;
    const int nkc = ((K + 31) & ~31) >> 5;          // 1 or 2
    const short8 z8 = {0, 0, 0, 0, 0, 0, 0, 0};
    short8 Bf[2];
    {
        int kq0 = quad * 8;
        Bf[0] = (kq0 < K) ? *(const short8*)&f[fpx + kq0] : z8;
        Bf[1] = (nkc > 1) ? *(const short8*)&f[fpx + 32 + quad * 8] : z8;
    }
    __syncthreads();

    // ---- per-lane tap cells: n = quad, 4+quad, 8 (for all 4 g-regs)
    const int nA = quad, nB = 4 + quad;
    const bf16* nbA = neigh_s + ((hl + nA / 3) * 10 + wl + nA % 3) * (CC + 2);
    const bf16* nbB = neigh_s + ((hl + nB / 3) * 10 + wl + nB % 3) * (CC + 2);
    const bf16* nbC = neigh_s + ((hl + 2) * 10 + wl + 2) * (CC + 2);
    const int x32 = ((lane ^ 32) & 63) << 2;        // bpermute byte index
    const bool q0 = (quad == 0);
    const bool bhi = (quad >> 1) != 0;              // q bit1 (lane bit5)
    const bool blo = (quad & 1) != 0;               // q bit0 (lane bit4)
    const bool l4 = (l16 < 4);
    bf16* osl = out_s + ((wave << 6) + lane) * (CC + 2);

    const char* pk = (const char*)kwp + (((size_t)c0 * 36 + l16) * K + quad * 8) * 2;
    const int dkc = 36 * K * 2;
    const int d16 = 16 * K * 2;
    const int d32 = 32 * K * 2;

    #pragma unroll 2
    for (int c = 0; c < CC; ++c) {
        const float* kbc = kb_s + c * 40;
        f32x4 a0 = *(const f32x4*)(kbc + (quad << 2));       // j = 4q+r
        f32x4 a1 = *(const f32x4*)(kbc + 16 + (quad << 2));  // j = 16+4q+r
        f32x4 a2 = *(const f32x4*)(kbc + 32);                // j = 32+r (q0 only)
        #pragma unroll
        for (int ch = 0; ch < 2; ++ch) {
            if (ch >= nkc) break;
            bool kok = (ch * 32 + quad * 8) < K;
            short8 f0 = kok ? *(const short8*)(pk + ch * 64) : z8;
            short8 f1 = kok ? *(const short8*)(pk + d16 + ch * 64) : z8;
            short8 f2 = (kok && l4) ? *(const short8*)(pk + d32 + ch * 64) : z8;
            a0 = __builtin_amdgcn_mfma_f32_16x16x32_bf16(f0, Bf[ch], a0, 0, 0, 0);
            a1 = __builtin_amdgcn_mfma_f32_16x16x32_bf16(f1, Bf[ch], a1, 0, 0, 0);
            a2 = __builtin_amdgcn_mfma_f32_16x16x32_bf16(f2, Bf[ch], a2, 0, 0, 0);
        }
        pk += dkc;
        float nv0 = b2f(nbA[c]), nv1 = b2f(nbB[c]), nv8 = b2f(nbC[c]);
        float Vs[4], Va[4];
        #pragma unroll
        for (int r = 0; r < 4; ++r) {
            float e0 = __expf(a0[r]);
            float e1 = __expf(a1[r]);
            float e2 = __expf(a2[r]);
            float e2m = q0 ? e2 : 0.f;
            Vs[r] = e0 + e1 + e2m;
            Va[r] = fmaf(e0, nv0, fmaf(e1, nv1, e2m * nv8));
        }
        // transpose-reduce over quads; lane ends with row r = quad.
        float sd0 = bhi ? Vs[0] : Vs[2];
        float sd1 = bhi ? Vs[1] : Vs[3];
        float sa0 = bhi ? Va[0] : Va[2];
        float sa1 = bhi ? Va[1] : Va[3];
        float rs0 = __int_as_float(__builtin_amdgcn_ds_bpermute(x32, __float_as_int(sd0)));
        float rs1 = __int_as_float(__builtin_amdgcn_ds_bpermute(x32, __float_as_int(sd1)));
        float ra0 = __int_as_float(__builtin_amdgcn_ds_bpermute(x32, __float_as_int(sa0)));
        float ra1 = __int_as_float(__builtin_amdgcn_ds_bpermute(x32, __float_as_int(sa1)));
        float Ps0 = (bhi ? Vs[2] : Vs[0]) + rs0;
        float Ps1 = (bhi ? Vs[3] : Vs[1]) + rs1;
        float Pa0 = (bhi ? Va[2] : Va[0]) + ra0;
        float Pa1 = (bhi ? Va[3] : Va[1]) + ra1;
        float ss = blo ? Ps0 : Ps1;
        float sa = blo ? Pa0 : Pa1;
        float qs = __int_as_float(__builtin_amdgcn_ds_swizzle(__float_as_int(ss), 0x401F));
        float qa = __int_as_float(__builtin_amdgcn_ds_swizzle(__float_as_int(sa), 0x401F));
        float Ss = (blo ? Ps1 : Ps0) + qs;
        float Sa = (blo ? Pa1 : Pa0) + qa;
        osl[c] = f2b(__fdividef(Sa, Ss));
    }

    __syncthreads();
    // ---- coalesced write-out: slot s = (wave, quad, hb, wl) -> (row, col)
    const size_t obase = (size_t)b * 4 * H * W;
    for (int i = tid; i < 256 * CC; i += 256) {
        int c = i % CC, s = i / CC;
        int wv = s >> 6, q = (s >> 4) & 3, hb = (s >> 3) & 1, wls = s & 7;
        int row_l = (wls << 1) + (q & 1);               // 2w + v
        int col_l = (((wv << 1) + hb) << 1) + (q >> 1); // 2h + u
        size_t P = obase + (size_t)(2 * w0 + row_l) * (2 * W) + (2 * h0 + col_l);
        out[P * C + c0 + c] = out_s[s * (CC + 2) + c];
    }
}

// ---------------------------------------------------------------- fused memory-bank + final 1x1 conv
__global__ __launch_bounds__(256, 2) void memfuse_final(
        const bf16* __restrict__ x, const void* __restrict__ memw,
        const void* __restrict__ fw, const void* __restrict__ fb,
        const float* __restrict__ flg, void* __restrict__ out, int HW) {
    __shared__ float mns[64 * 32];
    __shared__ float fws[66];
    const bool isb = (*flg != 0.f);
    if (threadIdx.x < 64) {
        int s = threadIdx.x;
        float v[32];
        float ss = 0.f;
        #pragma unroll
        for (int c = 0; c < 32; ++c) { v[c] = ldin(memw, s * 32 + c, isb); ss += v[c] * v[c]; }
        float inv = 1.f / fmaxf(sqrtf(ss), 1e-12f);
        #pragma unroll
        for (int c = 0; c < 32; ++c) mns[s * 32 + c] = v[c] * inv;
    } else if (threadIdx.x < 128) {
        int t = threadIdx.x - 64;
        fws[t] = ldin(fw, t, isb);
    } else if (threadIdx.x == 128) {
        fws[64] = ldin(fb, 0, isb);
        fws[65] = ldin(fb, 1, isb);
    }
    __syncthreads();

    int idx = blockIdx.x * blockDim.x + threadIdx.x;
    const bf16* xp = x + (size_t)idx * 32;

    float feat[32];
    float ss = 0.f;
    #pragma unroll
    for (int c = 0; c < 32; ++c) { feat[c] = b2f(xp[c]); ss += feat[c] * feat[c]; }
    float inv2 = 1.4426950408889634f / fmaxf(sqrtf(ss), 1e-12f);

    float se = 0.f;
    float racc[32];
    #pragma unroll
    for (int c = 0; c < 32; ++c) racc[c] = 0.f;

    for (int s = 0; s < 64; ++s) {
        const float* mr = mns + s * 32;
        float dot = 0.f;
        #pragma unroll
        for (int c = 0; c < 32; ++c) dot = fmaf(feat[c], mr[c], dot);
        float e = ex2(dot * inv2);
        se += e;
        #pragma unroll
        for (int c = 0; c < 32; ++c) racc[c] = fmaf(e, mr[c], racc[c]);
    }
    float rse = 1.f / se;
    float a0 = fws[64], a1 = fws[65];
    #pragma unroll
    for (int c = 0; c < 32; ++c) {
        float y = feat[c] + racc[c] * rse;
        a0 = fmaf(y, fws[c], a0);
        a1 = fmaf(y, fws[32 + c], a1);
    }
    int b = idx / HW, p = idx % HW;
    size_t i0 = (size_t)b * 2 * HW + p;
    size_t i1 = i0 + HW;
    if (isb) { ((bf16*)out)[i0] = f2b(a0); ((bf16*)out)[i1] = f2b(a1); }
    else     { ((float*)out)[i0] = a0;     ((float*)out)[i1] = a1; }
}

// ================================================================ host
extern "C" void kernel_launch(void* const* d_in, const int* in_sizes, int n_in,
                              void* d_out, int out_size, void* d_ws, size_t ws_size,
                              hipStream_t stream) {
    const void* x0_0 = d_in[0];
    const void* x1_0 = d_in[1];
    const void* x2_0 = d_in[2];
    const void* x3_0 = d_in[3];
    const void* c3_w1 = d_in[4];  const void* c3_b1 = d_in[5];  const void* c3_a1 = d_in[6];
    const void* c3_w2 = d_in[7];  const void* c3_b2 = d_in[8];  const void* c3_a2 = d_in[9];
    const void* c3_kw = d_in[10]; const void* c3_kb = d_in[11];
    const void* c2_w1 = d_in[12]; const void* c2_b1 = d_in[13]; const void* c2_a1 = d_in[14];
    const void* c2_w2 = d_in[15]; const void* c2_b2 = d_in[16]; const void* c2_a2 = d_in[17];
    const void* c2_kw = d_in[18]; const void* c2_kb = d_in[19];
    const void* c1_w1 = d_in[20]; const void* c1_b1 = d_in[21]; const void* c1_a1 = d_in[22];
    const void* c1_w2 = d_in[23]; const void* c1_b2 = d_in[24]; const void* c1_a2 = d_in[25];
    const void* c1_kw = d_in[26]; const void* c1_kb = d_in[27];
    const void* b21_w1 = d_in[28]; const void* b21_b1 = d_in[29];
    const void* b21_w2 = d_in[30]; const void* b21_b2 = d_in[31];
    const void* b12_w1 = d_in[32]; const void* b12_b1 = d_in[33];
    const void* b12_w2 = d_in[34]; const void* b12_b2 = d_in[35];
    const void* b03_w1 = d_in[36]; const void* b03_b1 = d_in[37];
    const void* b03_w2 = d_in[38]; const void* b03_b2 = d_in[39];
    const void* fin_w = d_in[40];  const void* fin_b = d_in[41];
    const void* memw  = d_in[42];
    (void)in_sizes; (void)n_in;

    const int TB = 256;
    auto blocks = [](int n) { return (n + 255) / 256; };

    const size_t NEED = 25165824 + 65536;
    if (ws_size < NEED) {
        diag_fill<<<blocks(out_size / 2), TB, 0, stream>>>(
            (unsigned int*)d_out, out_size / 2, (float)ws_size);
        return;
    }
    const size_t NEED_X0 = 25165824 + 8388608 + 65536 + 256;
    const bool have_x0cl = (ws_size >= NEED_X0);

    size_t tail = (ws_size - 65536) & ~(size_t)255;
    bf16*  wtail = (bf16*)((char*)d_ws + tail);
    float* flg   = (float*)((char*)d_ws + tail + 63488);
    char*  zstrip = (char*)d_ws + tail + 63744;     // 1 KiB zero strip

    // 24 MiB arena (12,582,912 bf16 elems), channels-last, verified live ranges.
    bf16* A = (bf16*)d_ws;
    bf16* x3up  = A + 0;         // [2,64,64,256] (0..2097152)
    bf16* ctx3p = A + 2097152;   // [2,32,32,128]
    bf16* f3a   = A + 2359296;   // [2,32,32,128]
    bf16* f3b   = A + 2621440;   // [2,32,32,64]
    bf16* kw3p  = A + 3000000;   // 589,824 elems (3000000..3589824)
    bf16* t2a   = A + 2097152;   // [2,64,64,128] (2097152..3145728)
    bf16* x2cl  = A + 3145728;   // [2,64,64,128] (3145728..4194304)
    bf16* x2_1  = A + 0;         // [2,64,64,128] (0..1048576)
    bf16* ctx2  = A + 1048576;   // [2,64,64,64]
    bf16* f2a   = A + 1572864;   // [2,64,64,64]
    bf16* f2b_  = A + 2097152;   // [2,64,64,32]
    bf16* x2up  = A + 2359296;   // [2,128,128,128] (ends 6553600)
    bf16* t1a   = A + 0;         // [2,128,128,64] (0..2097152)
    bf16* x1cl  = A + 6995968;   // [2,128,128,64] (6995968..9093120)
    bf16* x1_2  = A + 10485760;  // [2,128,128,64] (10485760..12582912)
    bf16* ctx1  = A + 4194304;   // [2,128,128,32]
    bf16* f1a   = A + 5242880;   // [2,128,128,32]
    bf16* f1b   = A + 9437184;   // [2,128,128,16] (9437184..9961472)
    bf16* kw1p  = A + 8388608;   // caun1 kw: past x1up end (x1up = 0..8388608)
    bf16* x1up  = A + 0;         // [2,256,256,64] (0..8388608)
    bf16* t0a   = A + 8388608;   // [2,256,256,32] (8388608..12582912!)
    bf16* x0_3  = A + 0;         // [2,256,256,32] (0..4194304)
    bf16* wslot = A + 6553600;   // weight slot (6553600..6995968, above x2up end)
    bf16* bw2   = A + 4194304;   // b21_w2 slot (free during b21 stage)
    bf16* x0cl  = A + 12582912;  // [2,256,256,32] (only if have_x0cl)

    detect_kernel<<<1, 64, 0, stream>>>((const unsigned int*)x0_0, flg, (unsigned int*)zstrip);

    // fused pack launcher: up to 3 jobs (ci>0 wpack; ci==0 flat copy of co elems)
    auto pk3 = [&](const void* s0, bf16* d0, int co0, int ci0,
                   const void* s1, bf16* d1, int co1, int ci1,
                   const void* s2, bf16* d2, int co2, int ci2) {
        int n0 = ci0 ? co0 * ci0 * 9 : co0;
        int n1 = s1 ? (ci1 ? co1 * ci1 * 9 : co1) : 0;
        int n2 = s2 ? (ci2 ? co2 * ci2 * 9 : co2) : 0;
        int b0 = (n0 + 255) / 256, b1 = (n1 + 255) / 256, b2c = (n2 + 255) / 256;
        pack3<<<b0 + b1 + b2c, TB, 0, stream>>>(flg,
            s0, d0, co0, ci0, s1, d1, co1, ci1, s2, d2, co2, ci2, b0, b0 + b1);
    };
    auto cgN = [](int H, int W, int Cout, int RT) {
        return dim3(W >> 4, H / (4 * RT), 2 * (Cout >> 4));
    };

    if (have_x0cl)
        nchw2cl<<<2 * 1 * 1024, TB, 0, stream>>>(x0_0, flg, x0cl, 32, 65536);

    // ---- caun3: ctx = pool(x2_0) -> [2,32,32,128] cl
    pool2_cl<<<blocks(262144), TB, 0, stream>>>(x2_0, flg, ctx3p, 2, 128, 32, 32);
    pk3(c3_w1, wslot, 128, 128,
        c3_w2, wslot + 147456, 64, 128,
        c3_kw, kw3p, 256 * 36 * 64, 0);
    conv3x3_lds<1, 1><<<cgN(32, 32, 128, 1), TB, 0, stream>>>(
        nullptr, 0, ctx3p, 128, wslot, c3_b1, c3_a1, flg, zstrip, f3a, 32, 32, 128, 2);
    conv3x3_lds<1, 1><<<cgN(32, 32, 64, 1), TB, 0, stream>>>(
        nullptr, 0, f3a, 128, wslot + 147456, c3_b2, c3_a2, flg, zstrip, f3b, 32, 32, 64, 2);
    caun_v5<8><<<dim3(16, 2, 32), TB, 0, stream>>>(
        f3b, x3_0, 1, kw3p, c3_kb, flg, x3up, 256, 64, 32, 32);

    // ---- block21: cat(x2_0 -> cl [128], x3up cl[256]) -> 128 -> 128 @64x64
    nchw2cl<<<2 * 4 * 64, TB, 0, stream>>>(x2_0, flg, x2cl, 128, 4096);
    pk3(b21_w1, wslot, 128, 384,
        b21_w2, bw2, 128, 128,
        nullptr, nullptr, 0, 0);
    conv3x3_lds<1, 1><<<cgN(64, 64, 128, 1), TB, 0, stream>>>(
        x2cl, 128, x3up, 256, wslot, b21_b1, nullptr, flg, zstrip, t2a, 64, 64, 128, 1);
    conv3x3_lds<1, 1><<<cgN(64, 64, 128, 1), TB, 0, stream>>>(
        nullptr, 0, t2a, 128, bw2, b21_b2, nullptr, flg, zstrip, x2_1, 64, 64, 128, 1);

    // ---- caun2: ctx = pool(x1_0) -> [2,64,64,64] cl
    pool2_cl<<<blocks(524288), TB, 0, stream>>>(x1_0, flg, ctx2, 2, 64, 64, 64);
    pk3(c2_w1, wslot, 64, 64,
        c2_w2, wslot + 36864, 32, 64,
        c2_kw, wslot + 55296, 128 * 36 * 32, 0);
    conv3x3_lds<1, 1><<<cgN(64, 64, 64, 1), TB, 0, stream>>>(
        nullptr, 0, ctx2, 64, wslot, c2_b1, c2_a1, flg, zstrip, f2a, 64, 64, 64, 2);
    conv3x3_lds<1, 1><<<cgN(64, 64, 32, 1), TB, 0, stream>>>(
        nullptr, 0, f2a, 64, wslot + 36864, c2_b2, c2_a2, flg, zstrip, f2b_, 64, 64, 32, 2);
    caun_v5<8><<<dim3(64, 2, 16), TB, 0, stream>>>(
        f2b_, x2_1, 0, wslot + 55296, c2_kb, flg, x2up, 128, 32, 64, 64);

    // ---- block12: cat(x1_0 -> cl [64], x2up cl[128]) -> 64 -> 64 @128x128
    nchw2cl<<<2 * 2 * 256, TB, 0, stream>>>(x1_0, flg, x1cl, 64, 16384);
    pk3(b12_w1, wslot, 64, 192,
        b12_w2, wslot + 110592, 64, 64,
        nullptr, nullptr, 0, 0);
    conv3x3_lds<2, 1><<<cgN(128, 128, 64, 2), TB, 0, stream>>>(
        x1cl, 64, x2up, 128, wslot, b12_b1, nullptr, flg, zstrip, t1a, 128, 128, 64, 1);
    conv3x3_lds<2, 1><<<cgN(128, 128, 64, 2), TB, 0, stream>>>(
        nullptr, 0, t1a, 64, wslot + 110592, b12_b2, nullptr, flg, zstrip, x1_2, 128, 128, 64, 1);

    // ---- caun1: ctx = pool(x0_0) -> [2,128,128,32] cl
    pool2_cl<<<blocks(1048576), TB, 0, stream>>>(x0_0, flg, ctx1, 2, 32, 128, 128);
    pk3(c1_w1, wslot, 32, 32,
        c1_w2, wslot + 9216, 16, 32,
        c1_kw, kw1p, 64 * 36 * 16, 0);
    conv3x3_lds<1, 1><<<cgN(128, 128, 32, 1), TB, 0, stream>>>(
        nullptr, 0, ctx1, 32, wslot, c1_b1, c1_a1, flg, zstrip, f1a, 128, 128, 32, 2);
    conv3x3_lds<1, 1><<<cgN(128, 128, 16, 1), TB, 0, stream>>>(
        nullptr, 0, f1a, 32, wslot + 9216, c1_b2, c1_a2, flg, zstrip, f1b, 128, 128, 16, 2);
    caun_v5<8><<<dim3(256, 2, 8), TB, 0, stream>>>(
        f1b, x1_2, 0, kw1p, c1_kb, flg, x1up, 64, 16, 128, 128);

    // ---- block03: cat(x0_0 [32], x1up cl[64]) -> 32 -> 32 @256x256
    pk3(b03_w1, wtail, 32, 96, nullptr, nullptr, 0, 0, nullptr, nullptr, 0, 0);
    if (have_x0cl) {
        conv3x3_lds<2, 1><<<cgN(256, 256, 32, 2), TB, 0, stream>>>(
            x0cl, 32, x1up, 64, wtail, b03_b1, nullptr, flg, zstrip, t0a, 256, 256, 32, 1);
    } else {
        conv3x3_ext<4><<<dim3(16, 16, 4), TB, 0, stream>>>(
            x0_0, 32, x1up, 64, wtail, b03_b1, nullptr, flg, t0a, 256, 256, 32, 1);
    }
    pk3(b03_w2, wtail, 32, 32, nullptr, nullptr, 0, 0, nullptr, nullptr, 0, 0);
    conv3x3_lds<2, 1><<<cgN(256, 256, 32, 2), TB, 0, stream>>>(
        nullptr, 0, t0a, 32, wtail, b03_b2, nullptr, flg, zstrip, x0_3, 256, 256, 32, 1);

    // ---- fused memory-bank residual + final 1x1 conv -> [2,2,256,256]
    memfuse_final<<<512, TB, 0, stream>>>(x0_3, memw, fin_w, fin_b, flg, d_out, 256 * 256);
}